// Round 14
// baseline (776.987 us; speedup 1.0000x reference)
//
#include <hip/hip_runtime.h>
#include <hip/hip_bf16.h>

// Problem constants fixed by setup_inputs()
#define NNODE   20000
#define BS      8
#define NEG1    33
#define DDIM    32
#define NLAYER  6
#define NRELX2  128     // 2*N_REL
#define FEAT    256     // BS*DDIM
#define INW     416     // 13*DDIM
#define NPB     8       // nodes per block, ONE group -> grid 2500
#define WTOT    (32 * 416)   // 13312 floats = 52 KB weight table per layer

// ---------------------------------------------------------------- precompute
__global__ void count_kernel(const int* __restrict__ es, const int* __restrict__ ed,
                             int* __restrict__ cnt, int E) {
    int i = blockIdx.x * 256 + threadIdx.x;
    if (i >= 2 * E) return;
    int dst = (i < E) ? ed[i] : es[i - E];
    atomicAdd(&cnt[dst], 1);
}

__global__ void scan_kernel(const int* __restrict__ cnt, int* __restrict__ row_ptr, int N) {
    __shared__ int sh[1024];
    __shared__ int s_carry;
    if (threadIdx.x == 0) { s_carry = 0; row_ptr[0] = 0; }
    __syncthreads();
    for (int base = 0; base < N; base += 1024) {
        int i = base + threadIdx.x;
        int v = (i < N) ? cnt[i] : 0;
        sh[threadIdx.x] = v;
        __syncthreads();
        for (int off = 1; off < 1024; off <<= 1) {
            int t = (threadIdx.x >= off) ? sh[threadIdx.x - off] : 0;
            __syncthreads();
            sh[threadIdx.x] += t;
            __syncthreads();
        }
        int carry = s_carry;
        if (i < N) row_ptr[i + 1] = carry + sh[threadIdx.x];
        __syncthreads();
        if (threadIdx.x == 1023) s_carry = carry + sh[1023];
        __syncthreads();
    }
}

// csr_pack = (src << 16) | etype   (src < 20000 < 65536, etype < 128)
__global__ void fill_kernel(const int* __restrict__ es, const int* __restrict__ ed,
                            const int* __restrict__ et, const int* __restrict__ row_ptr,
                            int* __restrict__ cursor, int* __restrict__ csr_pack, int E) {
    int i = blockIdx.x * 256 + threadIdx.x;
    if (i >= 2 * E) return;
    int src, dst, ty;
    if (i < E) { src = es[i]; dst = ed[i]; ty = et[i]; }
    else       { src = ed[i - E]; dst = es[i - E]; ty = et[i - E] + 64; }
    int pos = row_ptr[dst] + atomicAdd(&cursor[dst], 1);
    csr_pack[pos] = (src << 16) | ty;
}

__global__ void deg_kernel(const int* __restrict__ cnt, float* __restrict__ dinv,
                           float* __restrict__ logdeg, int N) {
    int n = blockIdx.x * 256 + threadIdx.x;
    if (n >= N) return;
    float deg = (float)cnt[n] + 1.0f;
    dinv[n] = 1.0f / deg;
    logdeg[n] = logf(deg);
}

__global__ void mean_kernel(const float* __restrict__ logdeg, float* __restrict__ meanout, int N) {
    __shared__ float sh[256];
    float s = 0.f;
    for (int i = threadIdx.x; i < N; i += 256) s += logdeg[i];
    sh[threadIdx.x] = s;
    __syncthreads();
    for (int off = 128; off > 0; off >>= 1) {
        if (threadIdx.x < off) sh[threadIdx.x] += sh[threadIdx.x + off];
        __syncthreads();
    }
    if (threadIdx.x == 0) meanout[0] = sh[0] / (float)N;
}

__global__ void sc_kernel(const float* __restrict__ logdeg, const float* __restrict__ meanp,
                          float* __restrict__ sc, int N) {
    int n = blockIdx.x * 256 + threadIdx.x;
    if (n >= N) return;
    sc[n] = logdeg[n] / meanp[0];
}

__global__ void prep_kernel(const int* __restrict__ h_index, const int* __restrict__ t_index,
                            const int* __restrict__ r_index, const float* __restrict__ rel_query,
                            int* __restrict__ h0, int* __restrict__ r0,
                            float* __restrict__ query, int* __restrict__ tnew) {
    __shared__ int s_isneg[BS];
    __shared__ int s_r0[BS];
    int t = threadIdx.x;
    if (t < BS) {
        int b = t;
        int hv = h_index[b * NEG1];
        int all = 1;
        for (int j = 1; j < NEG1; j++) all &= (h_index[b * NEG1 + j] == hv);
        s_isneg[b] = all;
        int h0v = all ? hv : t_index[b * NEG1];
        int r0v = all ? r_index[b * NEG1] : r_index[b * NEG1] + 64;
        s_r0[b] = r0v;
        h0[b] = h0v;
        r0[b] = r0v;
    }
    __syncthreads();
    {
        int b = t >> 5, dd = t & 31;
        query[t] = rel_query[s_r0[b] * DDIM + dd];
    }
    for (int idx = t; idx < BS * NEG1; idx += 256) {
        int b = idx / NEG1;
        tnew[idx] = s_isneg[b] ? t_index[idx] : h_index[idx];
    }
}

__global__ void rel_kernel(const float* __restrict__ rel_query, const float* __restrict__ Wrel,
                           const float* __restrict__ brel, float* __restrict__ rel_all) {
    int idx = blockIdx.x * 256 + threadIdx.x;
    if (idx >= NLAYER * NRELX2 * DDIM) return;
    int i  = idx >> 12;          // / 4096
    int q  = (idx >> 5) & 127;
    int dd = idx & 31;
    float acc = brel[i * DDIM + dd];
    #pragma unroll
    for (int k = 0; k < DDIM; k++)
        acc = fmaf(rel_query[q * DDIM + k], Wrel[i * DDIM * DDIM + k * DDIM + dd], acc);
    rel_all[idx] = acc;
}

// Wg[layer][step][j][dd] = Wlin[layer][k_j(dd)][(dd+step)&31]
__global__ void wg_kernel(const float* __restrict__ Wlin, float* __restrict__ wg) {
    int idx = blockIdx.x * 256 + threadIdx.x;       // NLAYER*32*13*32
    if (idx >= NLAYER * 32 * 13 * 32) return;
    int dd = idx & 31;
    int r  = idx >> 5;
    int j  = r % 13;
    int r2 = r / 13;
    int step  = r2 & 31;
    int layer = r2 >> 5;
    int k;
    if (j == 0) k = dd;
    else { int s = (j - 1) / 3, scl = (j - 1) % 3; k = 32 + (dd * 4 + s) * 3 + scl; }
    int col = (dd + step) & 31;
    wg[idx] = Wlin[(layer * INW + k) * DDIM + col];
}

__global__ void init_x_kernel(float* __restrict__ x, const int* __restrict__ h0,
                              const float* __restrict__ query) {
    int i = blockIdx.x * 256 + threadIdx.x;
    if (i >= NNODE * FEAT) return;
    int n = i >> 8;
    int t = i & 255;
    int b = t >> 5;
    x[i] = (h0[b] == n) ? query[t] : 0.f;
}

// ---------------------------------------------------------------- main layer
// Per block: 8 nodes, ONE group. PRESCALED 13 stats/node -> GSTEP is a pure
// 13-FMA dot (no recombination). Weight table (52 KB) staged in LDS (union
// buffer with the 16 KB rel table, sequential phases) -> ds_read weights,
// no global-load latency in the GEMM loop, no register double-buffer.

#define STATS_COMP(U, NODE) {                                                 \
    int n_ = (NODE);                                                          \
    float bv_ = (h0b == n_) ? q : 0.f;                                        \
    float sum_ = bv_, ssq_ = bv_ * bv_, vmx_ = bv_, vmn_ = bv_;               \
    int e0_ = row_ptr[n_], e1_ = row_ptr[n_ + 1];                             \
    ps0##U = x_in[n_ * FEAT + t];                                             \
    int e_ = e0_;                                                             \
    for (; e_ + 3 < e1_; e_ += 4) {                                           \
        int pa_ = csr_pack[e_];                                               \
        int pb_ = csr_pack[e_ + 1];                                           \
        int pc_ = csr_pack[e_ + 2];                                           \
        int pd_ = csr_pack[e_ + 3];                                           \
        float xa_ = x_in[(pa_ >> 16) * FEAT + t];                             \
        float xb_ = x_in[(pb_ >> 16) * FEAT + t];                             \
        float xc_ = x_in[(pc_ >> 16) * FEAT + t];                             \
        float xd_ = x_in[(pd_ >> 16) * FEAT + t];                             \
        float ra_ = s_mem[((pa_ & 0xFFFF) << 5) + dd];                        \
        float rb_ = s_mem[((pb_ & 0xFFFF) << 5) + dd];                        \
        float rc_ = s_mem[((pc_ & 0xFFFF) << 5) + dd];                        \
        float rd_ = s_mem[((pd_ & 0xFFFF) << 5) + dd];                        \
        float ma_ = xa_ * ra_, mb_ = xb_ * rb_;                               \
        float mc_ = xc_ * rc_, md_ = xd_ * rd_;                               \
        sum_ += ((ma_ + mb_) + (mc_ + md_));                                  \
        ssq_ = fmaf(ma_, ma_, ssq_); ssq_ = fmaf(mb_, mb_, ssq_);             \
        ssq_ = fmaf(mc_, mc_, ssq_); ssq_ = fmaf(md_, md_, ssq_);             \
        vmx_ = fmaxf(vmx_, fmaxf(fmaxf(ma_, mb_), fmaxf(mc_, md_)));         \
        vmn_ = fminf(vmn_, fminf(fminf(ma_, mb_), fminf(mc_, md_)));         \
    }                                                                         \
    for (; e_ < e1_; ++e_) {                                                  \
        int p_  = csr_pack[e_];                                               \
        float m_ = x_in[(p_ >> 16) * FEAT + t]                                \
                   * s_mem[((p_ & 0xFFFF) << 5) + dd];                        \
        sum_ += m_; ssq_ = fmaf(m_, m_, ssq_);                                \
        vmx_ = fmaxf(vmx_, m_); vmn_ = fminf(vmn_, m_);                       \
    }                                                                         \
    float dv_ = dinv[n_];                                                     \
    float me_ = sum_ * dv_;                                                   \
    float sq_ = ssq_ * dv_;                                                   \
    float sd_ = sqrtf(fmaxf(sq_ - me_ * me_, 1e-6f));                         \
    float sv_ = sc[n_];                                                       \
    float s2_ = 1.0f / fmaxf(sv_, 0.01f);                                     \
    ps1##U  = me_;  ps2##U  = me_ * sv_;  ps3##U  = me_ * s2_;                \
    ps4##U  = vmx_; ps5##U  = vmx_ * sv_; ps6##U  = vmx_ * s2_;               \
    ps7##U  = vmn_; ps8##U  = vmn_ * sv_; ps9##U  = vmn_ * s2_;               \
    ps10##U = sd_;  ps11##U = sd_ * sv_;  ps12##U = sd_ * s2_;                \
}

#define SDECL(U) float ps0##U, ps1##U, ps2##U, ps3##U, ps4##U, ps5##U,        \
    ps6##U, ps7##U, ps8##U, ps9##U, ps10##U, ps11##U, ps12##U;

#define GSTEP(U) {                                                            \
    float a_ = acc##U;                                                        \
    a_ = fmaf(ps0##U,  w0,  a_);                                              \
    a_ = fmaf(ps1##U,  w1,  a_);                                              \
    a_ = fmaf(ps2##U,  w2,  a_);                                              \
    a_ = fmaf(ps3##U,  w3,  a_);                                              \
    a_ = fmaf(ps4##U,  w4,  a_);                                              \
    a_ = fmaf(ps5##U,  w5,  a_);                                              \
    a_ = fmaf(ps6##U,  w6,  a_);                                              \
    a_ = fmaf(ps7##U,  w7,  a_);                                              \
    a_ = fmaf(ps8##U,  w8,  a_);                                              \
    a_ = fmaf(ps9##U,  w9,  a_);                                              \
    a_ = fmaf(ps10##U, w10, a_);                                              \
    a_ = fmaf(ps11##U, w11, a_);                                              \
    a_ = fmaf(ps12##U, w12, a_);                                              \
    acc##U = a_;                                                              \
}

#define ROT(U) acc##U = __int_as_float(__builtin_amdgcn_ds_bpermute(          \
                            bperm_addr, __float_as_int(acc##U)));

#define LNSTORE(U, NODE) {                                                    \
    int n_ = (NODE);                                                          \
    float v_ = acc##U;                                                        \
    float s1_ = v_;                                                           \
    s1_ += __shfl_xor(s1_, 16, 32); s1_ += __shfl_xor(s1_, 8, 32);            \
    s1_ += __shfl_xor(s1_, 4, 32);  s1_ += __shfl_xor(s1_, 2, 32);            \
    s1_ += __shfl_xor(s1_, 1, 32);                                            \
    float lm_ = s1_ * (1.0f / 32.0f);                                         \
    float dl_ = v_ - lm_;                                                     \
    float p2_ = dl_ * dl_;                                                    \
    p2_ += __shfl_xor(p2_, 16, 32); p2_ += __shfl_xor(p2_, 8, 32);            \
    p2_ += __shfl_xor(p2_, 4, 32);  p2_ += __shfl_xor(p2_, 2, 32);            \
    p2_ += __shfl_xor(p2_, 1, 32);                                            \
    float var_ = p2_ * (1.0f / 32.0f);                                        \
    float y_ = dl_ / sqrtf(var_ + 1e-5f) * gdd + bdd;                         \
    y_ = fmaxf(y_, 0.0f);                                                     \
    x_out[n_ * FEAT + t] = y_ + ps0##U;                                       \
}

__global__ __launch_bounds__(256, 2) void layer_kernel(
    const float* __restrict__ x_in, float* __restrict__ x_out,
    const int* __restrict__ row_ptr, const int* __restrict__ csr_pack,
    const float* __restrict__ rel_i,     // [128][32]
    const float* __restrict__ wg_i,      // [32][13][32] step-contiguous
    const float* __restrict__ blin_i, const float* __restrict__ g_i,
    const float* __restrict__ b_i,
    const float* __restrict__ dinv, const float* __restrict__ sc,
    const int* __restrict__ h0, const float* __restrict__ query) {
    int t  = threadIdx.x;
    int b  = t >> 5, dd = t & 31;
    int lane = t & 63;
    __shared__ float s_mem[WTOT];   // 52 KB union: rel (16 KB) then weights

    // phase 1: rel table into LDS
    for (int k = t; k < NRELX2 * DDIM; k += 256) s_mem[k] = rel_i[k];

    float q   = query[t];
    int   h0b = h0[b];
    float gdd = g_i[dd], bdd = b_i[dd], bl = blin_i[dd];
    // rotate-down-by-1 within each 32-lane half of the wave (pull from lane+1)
    int bperm_addr = ((((lane + 1) & 31) | (lane & 32)) << 2);
    __syncthreads();

    int nbase = blockIdx.x * NPB;
    SDECL(0) SDECL(1) SDECL(2) SDECL(3)
    SDECL(4) SDECL(5) SDECL(6) SDECL(7)
    STATS_COMP(0, nbase + 0)
    STATS_COMP(1, nbase + 1)
    STATS_COMP(2, nbase + 2)
    STATS_COMP(3, nbase + 3)
    STATS_COMP(4, nbase + 4)
    STATS_COMP(5, nbase + 5)
    STATS_COMP(6, nbase + 6)
    STATS_COMP(7, nbase + 7)

    // phase 2: weight table into LDS (overwrites rel region)
    __syncthreads();
    for (int k = t; k < WTOT; k += 256) s_mem[k] = wg_i[k];
    __syncthreads();

    float acc0 = bl, acc1 = bl, acc2 = bl, acc3 = bl;
    float acc4 = bl, acc5 = bl, acc6 = bl, acc7 = bl;

    #pragma unroll 1
    for (int i = 0; i < 32; ++i) {
        const float* wl = s_mem + i * 416 + dd;
        float w0  = wl[0 * 32],  w1  = wl[1 * 32],  w2  = wl[2 * 32];
        float w3  = wl[3 * 32],  w4  = wl[4 * 32],  w5  = wl[5 * 32];
        float w6  = wl[6 * 32],  w7  = wl[7 * 32],  w8  = wl[8 * 32];
        float w9  = wl[9 * 32],  w10 = wl[10 * 32], w11 = wl[11 * 32];
        float w12 = wl[12 * 32];
        GSTEP(0) GSTEP(1) GSTEP(2) GSTEP(3)
        GSTEP(4) GSTEP(5) GSTEP(6) GSTEP(7)
        ROT(0) ROT(1) ROT(2) ROT(3)
        ROT(4) ROT(5) ROT(6) ROT(7)
    }
    // 32 rotations = identity: lane dd again holds col dd

    LNSTORE(0, nbase + 0)
    LNSTORE(1, nbase + 1)
    LNSTORE(2, nbase + 2)
    LNSTORE(3, nbase + 3)
    LNSTORE(4, nbase + 4)
    LNSTORE(5, nbase + 5)
    LNSTORE(6, nbase + 6)
    LNSTORE(7, nbase + 7)
}

// ---------------------------------------------------------------- readout
__global__ void score_kernel(const float* __restrict__ x, const int* __restrict__ tnew,
                             const float* __restrict__ query,
                             const float* __restrict__ W1, const float* __restrict__ b1,
                             const float* __restrict__ W2, const float* __restrict__ b2,
                             float* __restrict__ out) {
    int idx = blockIdx.x;         // b*33+j
    int b = idx / NEG1;
    int k = threadIdx.x;          // 0..63
    __shared__ float v[64];
    int tnode = tnew[idx];
    if (k < 32) v[k] = x[tnode * FEAT + b * DDIM + k];
    else        v[k] = query[b * DDIM + (k - 32)];
    __syncthreads();
    float acc = b1[k];
    #pragma unroll
    for (int l = 0; l < 64; l++) acc = fmaf(v[l], W1[l * 64 + k], acc);
    acc = fmaxf(acc, 0.f);
    float p = acc * W2[k];
    #pragma unroll
    for (int m = 32; m >= 1; m >>= 1) p += __shfl_xor(p, m);
    if (k == 0) out[idx] = p + b2[0];
}

// ---------------------------------------------------------------- launch
extern "C" void kernel_launch(void* const* d_in, const int* in_sizes, int n_in,
                              void* d_out, int out_size, void* d_ws, size_t ws_size,
                              hipStream_t stream) {
    const int* edge_src  = (const int*)d_in[0];
    const int* edge_dst  = (const int*)d_in[1];
    const int* edge_type = (const int*)d_in[2];
    const int* h_index   = (const int*)d_in[3];
    const int* t_index   = (const int*)d_in[4];
    const int* r_index   = (const int*)d_in[5];
    const float* rel_query = (const float*)d_in[7];
    const float* Wrel    = (const float*)d_in[8];
    const float* brel    = (const float*)d_in[9];
    const float* Wlin    = (const float*)d_in[10];
    const float* blin    = (const float*)d_in[11];
    const float* ln_g    = (const float*)d_in[12];
    const float* ln_b    = (const float*)d_in[13];
    const float* W1      = (const float*)d_in[14];
    const float* b1      = (const float*)d_in[15];
    const float* W2      = (const float*)d_in[16];
    const float* b2      = (const float*)d_in[17];

    const int N  = NNODE;
    const int E  = in_sizes[0];
    const int E2 = 2 * E;

    char* p = (char*)d_ws;
    auto carve = [&](size_t bytes) {
        void* r = (void*)p;
        p += (bytes + 255) & ~(size_t)255;
        return r;
    };
    float* x0      = (float*)carve((size_t)N * FEAT * 4);
    float* x1      = (float*)carve((size_t)N * FEAT * 4);
    int*   cnt     = (int*)carve((size_t)N * 4);
    int*   row_ptr = (int*)carve((size_t)(N + 1) * 4);
    int*   cursor  = (int*)carve((size_t)N * 4);
    int*   csr_pack= (int*)carve((size_t)E2 * 4);
    float* dinv    = (float*)carve((size_t)N * 4);
    float* logdeg  = (float*)carve((size_t)N * 4);
    float* scn     = (float*)carve((size_t)N * 4);
    float* meanp   = (float*)carve(16);
    float* rel_all = (float*)carve((size_t)NLAYER * NRELX2 * DDIM * 4);
    float* wg      = (float*)carve((size_t)NLAYER * WTOT * 4);
    int*   h0      = (int*)carve(BS * 4);
    int*   r0      = (int*)carve(BS * 4);
    float* query   = (float*)carve(BS * DDIM * 4);
    int*   tnew    = (int*)carve(BS * NEG1 * 4);

    hipMemsetAsync(cnt, 0, (size_t)N * 4, stream);
    hipMemsetAsync(cursor, 0, (size_t)N * 4, stream);

    int eb = (E2 + 255) / 256;
    count_kernel<<<eb, 256, 0, stream>>>(edge_src, edge_dst, cnt, E);
    scan_kernel<<<1, 1024, 0, stream>>>(cnt, row_ptr, N);
    fill_kernel<<<eb, 256, 0, stream>>>(edge_src, edge_dst, edge_type, row_ptr,
                                        cursor, csr_pack, E);
    deg_kernel<<<(N + 255) / 256, 256, 0, stream>>>(cnt, dinv, logdeg, N);
    mean_kernel<<<1, 256, 0, stream>>>(logdeg, meanp, N);
    sc_kernel<<<(N + 255) / 256, 256, 0, stream>>>(logdeg, meanp, scn, N);
    prep_kernel<<<1, 256, 0, stream>>>(h_index, t_index, r_index, rel_query,
                                       h0, r0, query, tnew);
    rel_kernel<<<(NLAYER * NRELX2 * DDIM + 255) / 256, 256, 0, stream>>>(
        rel_query, Wrel, brel, rel_all);
    wg_kernel<<<(NLAYER * 32 * 13 * 32 + 255) / 256, 256, 0, stream>>>(Wlin, wg);
    init_x_kernel<<<(N * FEAT + 255) / 256, 256, 0, stream>>>(x0, h0, query);

    float* xin = x0;
    float* xout = x1;
    for (int i = 0; i < NLAYER; ++i) {
        layer_kernel<<<N / NPB, 256, 0, stream>>>(
            xin, xout, row_ptr, csr_pack,
            rel_all + (size_t)i * NRELX2 * DDIM,
            wg + (size_t)i * WTOT,
            blin + (size_t)i * DDIM,
            ln_g + (size_t)i * DDIM,
            ln_b + (size_t)i * DDIM,
            dinv, scn, h0, query);
        float* tmp = xin; xin = xout; xout = tmp;
    }

    score_kernel<<<BS * NEG1, 64, 0, stream>>>(xin, tnew, query, W1, b1, W2, b2,
                                               (float*)d_out);
}

// Round 15
// 654.453 us; speedup vs baseline: 1.1872x; 1.1872x over previous
//
#include <hip/hip_runtime.h>
#include <hip/hip_bf16.h>

// Problem constants fixed by setup_inputs()
#define NNODE   20000
#define BS      8
#define NEG1    33
#define DDIM    32
#define NLAYER  6
#define NRELX2  128     // 2*N_REL
#define FEAT    256     // BS*DDIM
#define INW     416     // 13*DDIM
#define NPB     10      // nodes per block, ONE group -> grid 2000

// ---------------------------------------------------------------- precompute
__global__ void count_kernel(const int* __restrict__ es, const int* __restrict__ ed,
                             int* __restrict__ cnt, int E) {
    int i = blockIdx.x * 256 + threadIdx.x;
    if (i >= 2 * E) return;
    int dst = (i < E) ? ed[i] : es[i - E];
    atomicAdd(&cnt[dst], 1);
}

__global__ void scan_kernel(const int* __restrict__ cnt, int* __restrict__ row_ptr, int N) {
    __shared__ int sh[1024];
    __shared__ int s_carry;
    if (threadIdx.x == 0) { s_carry = 0; row_ptr[0] = 0; }
    __syncthreads();
    for (int base = 0; base < N; base += 1024) {
        int i = base + threadIdx.x;
        int v = (i < N) ? cnt[i] : 0;
        sh[threadIdx.x] = v;
        __syncthreads();
        for (int off = 1; off < 1024; off <<= 1) {
            int t = (threadIdx.x >= off) ? sh[threadIdx.x - off] : 0;
            __syncthreads();
            sh[threadIdx.x] += t;
            __syncthreads();
        }
        int carry = s_carry;
        if (i < N) row_ptr[i + 1] = carry + sh[threadIdx.x];
        __syncthreads();
        if (threadIdx.x == 1023) s_carry = carry + sh[1023];
        __syncthreads();
    }
}

// csr_pack = (src << 16) | etype   (src < 20000 < 65536, etype < 128)
__global__ void fill_kernel(const int* __restrict__ es, const int* __restrict__ ed,
                            const int* __restrict__ et, const int* __restrict__ row_ptr,
                            int* __restrict__ cursor, int* __restrict__ csr_pack, int E) {
    int i = blockIdx.x * 256 + threadIdx.x;
    if (i >= 2 * E) return;
    int src, dst, ty;
    if (i < E) { src = es[i]; dst = ed[i]; ty = et[i]; }
    else       { src = ed[i - E]; dst = es[i - E]; ty = et[i - E] + 64; }
    int pos = row_ptr[dst] + atomicAdd(&cursor[dst], 1);
    csr_pack[pos] = (src << 16) | ty;
}

__global__ void deg_kernel(const int* __restrict__ cnt, float* __restrict__ dinv,
                           float* __restrict__ logdeg, int N) {
    int n = blockIdx.x * 256 + threadIdx.x;
    if (n >= N) return;
    float deg = (float)cnt[n] + 1.0f;
    dinv[n] = 1.0f / deg;
    logdeg[n] = logf(deg);
}

__global__ void mean_kernel(const float* __restrict__ logdeg, float* __restrict__ meanout, int N) {
    __shared__ float sh[256];
    float s = 0.f;
    for (int i = threadIdx.x; i < N; i += 256) s += logdeg[i];
    sh[threadIdx.x] = s;
    __syncthreads();
    for (int off = 128; off > 0; off >>= 1) {
        if (threadIdx.x < off) sh[threadIdx.x] += sh[threadIdx.x + off];
        __syncthreads();
    }
    if (threadIdx.x == 0) meanout[0] = sh[0] / (float)N;
}

__global__ void sc_kernel(const float* __restrict__ logdeg, const float* __restrict__ meanp,
                          float* __restrict__ sc, int N) {
    int n = blockIdx.x * 256 + threadIdx.x;
    if (n >= N) return;
    sc[n] = logdeg[n] / meanp[0];
}

__global__ void prep_kernel(const int* __restrict__ h_index, const int* __restrict__ t_index,
                            const int* __restrict__ r_index, const float* __restrict__ rel_query,
                            int* __restrict__ h0, int* __restrict__ r0,
                            float* __restrict__ query, int* __restrict__ tnew) {
    __shared__ int s_isneg[BS];
    __shared__ int s_r0[BS];
    int t = threadIdx.x;
    if (t < BS) {
        int b = t;
        int hv = h_index[b * NEG1];
        int all = 1;
        for (int j = 1; j < NEG1; j++) all &= (h_index[b * NEG1 + j] == hv);
        s_isneg[b] = all;
        int h0v = all ? hv : t_index[b * NEG1];
        int r0v = all ? r_index[b * NEG1] : r_index[b * NEG1] + 64;
        s_r0[b] = r0v;
        h0[b] = h0v;
        r0[b] = r0v;
    }
    __syncthreads();
    {
        int b = t >> 5, dd = t & 31;
        query[t] = rel_query[s_r0[b] * DDIM + dd];
    }
    for (int idx = t; idx < BS * NEG1; idx += 256) {
        int b = idx / NEG1;
        tnew[idx] = s_isneg[b] ? t_index[idx] : h_index[idx];
    }
}

__global__ void rel_kernel(const float* __restrict__ rel_query, const float* __restrict__ Wrel,
                           const float* __restrict__ brel, float* __restrict__ rel_all) {
    int idx = blockIdx.x * 256 + threadIdx.x;
    if (idx >= NLAYER * NRELX2 * DDIM) return;
    int i  = idx >> 12;          // / 4096
    int q  = (idx >> 5) & 127;
    int dd = idx & 31;
    float acc = brel[i * DDIM + dd];
    #pragma unroll
    for (int k = 0; k < DDIM; k++)
        acc = fmaf(rel_query[q * DDIM + k], Wrel[i * DDIM * DDIM + k * DDIM + dd], acc);
    rel_all[idx] = acc;
}

// Wg[layer][step][j][dd] = Wlin[layer][k_j(dd)][(dd+step)&31]
__global__ void wg_kernel(const float* __restrict__ Wlin, float* __restrict__ wg) {
    int idx = blockIdx.x * 256 + threadIdx.x;       // NLAYER*32*13*32
    if (idx >= NLAYER * 32 * 13 * 32) return;
    int dd = idx & 31;
    int r  = idx >> 5;
    int j  = r % 13;
    int r2 = r / 13;
    int step  = r2 & 31;
    int layer = r2 >> 5;
    int k;
    if (j == 0) k = dd;
    else { int s = (j - 1) / 3, scl = (j - 1) % 3; k = 32 + (dd * 4 + s) * 3 + scl; }
    int col = (dd + step) & 31;
    wg[idx] = Wlin[(layer * INW + k) * DDIM + col];
}

__global__ void init_x_kernel(float* __restrict__ x, const int* __restrict__ h0,
                              const float* __restrict__ query) {
    int i = blockIdx.x * 256 + threadIdx.x;
    if (i >= NNODE * FEAT) return;
    int n = i >> 8;
    int t = i & 255;
    int b = t >> 5;
    x[i] = (h0[b] == n) ? query[t] : 0.f;
}

// ---------------------------------------------------------------- main layer
// Per block: 10 nodes, ONE group, 7 raw stats/node. GEMM: systolic rotation;
// ROT(u) interleaved right after GSTEP(u) so each ds_bpermute has ~117 FMAs
// of slack before its next-step consumer (kills the per-step LDS bubble);
// weight double-buffer ping-pongs via explicit 2x unroll (no mov chain).

#define STATS_COMP(U, NODE) {                                                 \
    int n_ = (NODE);                                                          \
    float bv_ = (h0b == n_) ? q : 0.f;                                        \
    float sum_ = bv_, ssq_ = bv_ * bv_, vmx_ = bv_, vmn_ = bv_;               \
    int e0_ = row_ptr[n_], e1_ = row_ptr[n_ + 1];                             \
    xm##U = x_in[n_ * FEAT + t];                                              \
    int e_ = e0_;                                                             \
    for (; e_ + 3 < e1_; e_ += 4) {                                           \
        int pa_ = csr_pack[e_];                                               \
        int pb_ = csr_pack[e_ + 1];                                           \
        int pc_ = csr_pack[e_ + 2];                                           \
        int pd_ = csr_pack[e_ + 3];                                           \
        float xa_ = x_in[(pa_ >> 16) * FEAT + t];                             \
        float xb_ = x_in[(pb_ >> 16) * FEAT + t];                             \
        float xc_ = x_in[(pc_ >> 16) * FEAT + t];                             \
        float xd_ = x_in[(pd_ >> 16) * FEAT + t];                             \
        float ra_ = s_rel[((pa_ & 0xFFFF) << 5) + dd];                        \
        float rb_ = s_rel[((pb_ & 0xFFFF) << 5) + dd];                        \
        float rc_ = s_rel[((pc_ & 0xFFFF) << 5) + dd];                        \
        float rd_ = s_rel[((pd_ & 0xFFFF) << 5) + dd];                        \
        float ma_ = xa_ * ra_, mb_ = xb_ * rb_;                               \
        float mc_ = xc_ * rc_, md_ = xd_ * rd_;                               \
        sum_ += ((ma_ + mb_) + (mc_ + md_));                                  \
        ssq_ = fmaf(ma_, ma_, ssq_); ssq_ = fmaf(mb_, mb_, ssq_);             \
        ssq_ = fmaf(mc_, mc_, ssq_); ssq_ = fmaf(md_, md_, ssq_);             \
        vmx_ = fmaxf(vmx_, fmaxf(fmaxf(ma_, mb_), fmaxf(mc_, md_)));         \
        vmn_ = fminf(vmn_, fminf(fminf(ma_, mb_), fminf(mc_, md_)));         \
    }                                                                         \
    for (; e_ < e1_; ++e_) {                                                  \
        int p_  = csr_pack[e_];                                               \
        float m_ = x_in[(p_ >> 16) * FEAT + t]                                \
                   * s_rel[((p_ & 0xFFFF) << 5) + dd];                        \
        sum_ += m_; ssq_ = fmaf(m_, m_, ssq_);                                \
        vmx_ = fmaxf(vmx_, m_); vmn_ = fminf(vmn_, m_);                       \
    }                                                                         \
    float dv_ = dinv[n_];                                                     \
    mean##U = sum_ * dv_;                                                     \
    float sq_ = ssq_ * dv_;                                                   \
    mx##U = vmx_; mn##U = vmn_;                                               \
    sd##U = sqrtf(fmaxf(sq_ - mean##U * mean##U, 1e-6f));                     \
    float sv_ = sc[n_];                                                       \
    sv##U = sv_; s2##U = 1.0f / fmaxf(sv_, 0.01f);                            \
}

#define SDECL(U) float xm##U, mean##U, mx##U, mn##U, sd##U, sv##U, s2##U;

// GSTEP parameterized on weight register set (P = cw or nw)
#define GSTEP_W(U, P) {                                                       \
    float a_ = acc##U;                                                        \
    a_ = fmaf(xm##U, P##0, a_);                                               \
    float t0_ = fmaf(sv##U, P##2,  P##1);  t0_ = fmaf(s2##U, P##3,  t0_);     \
    a_ = fmaf(mean##U, t0_, a_);                                              \
    float t1_ = fmaf(sv##U, P##5,  P##4);  t1_ = fmaf(s2##U, P##6,  t1_);     \
    a_ = fmaf(mx##U,   t1_, a_);                                              \
    float t2_ = fmaf(sv##U, P##8,  P##7);  t2_ = fmaf(s2##U, P##9,  t2_);     \
    a_ = fmaf(mn##U,   t2_, a_);                                              \
    float t3_ = fmaf(sv##U, P##11, P##10); t3_ = fmaf(s2##U, P##12, t3_);     \
    a_ = fmaf(sd##U,   t3_, a_);                                              \
    acc##U = a_;                                                              \
}

#define ROT(U) acc##U = __int_as_float(__builtin_amdgcn_ds_bpermute(          \
                            bperm_addr, __float_as_int(acc##U)));

// one full systolic step with weights P, ROT interleaved after each GSTEP
#define STEP_ALL(P)                                                           \
    GSTEP_W(0, P) ROT(0) GSTEP_W(1, P) ROT(1)                                 \
    GSTEP_W(2, P) ROT(2) GSTEP_W(3, P) ROT(3)                                 \
    GSTEP_W(4, P) ROT(4) GSTEP_W(5, P) ROT(5)                                 \
    GSTEP_W(6, P) ROT(6) GSTEP_W(7, P) ROT(7)                                 \
    GSTEP_W(8, P) ROT(8) GSTEP_W(9, P) ROT(9)

#define LOADW(P, PTR)                                                         \
    P##0  = (PTR)[0 * 32];  P##1  = (PTR)[1 * 32];  P##2  = (PTR)[2 * 32];    \
    P##3  = (PTR)[3 * 32];  P##4  = (PTR)[4 * 32];  P##5  = (PTR)[5 * 32];    \
    P##6  = (PTR)[6 * 32];  P##7  = (PTR)[7 * 32];  P##8  = (PTR)[8 * 32];    \
    P##9  = (PTR)[9 * 32];  P##10 = (PTR)[10 * 32]; P##11 = (PTR)[11 * 32];   \
    P##12 = (PTR)[12 * 32];

#define LNSTORE(U, NODE) {                                                    \
    int n_ = (NODE);                                                          \
    float v_ = acc##U;                                                        \
    float s1_ = v_;                                                           \
    s1_ += __shfl_xor(s1_, 16, 32); s1_ += __shfl_xor(s1_, 8, 32);            \
    s1_ += __shfl_xor(s1_, 4, 32);  s1_ += __shfl_xor(s1_, 2, 32);            \
    s1_ += __shfl_xor(s1_, 1, 32);                                            \
    float lm_ = s1_ * (1.0f / 32.0f);                                         \
    float dl_ = v_ - lm_;                                                     \
    float p2_ = dl_ * dl_;                                                    \
    p2_ += __shfl_xor(p2_, 16, 32); p2_ += __shfl_xor(p2_, 8, 32);            \
    p2_ += __shfl_xor(p2_, 4, 32);  p2_ += __shfl_xor(p2_, 2, 32);            \
    p2_ += __shfl_xor(p2_, 1, 32);                                            \
    float var_ = p2_ * (1.0f / 32.0f);                                        \
    float y_ = dl_ / sqrtf(var_ + 1e-5f) * gdd + bdd;                         \
    y_ = fmaxf(y_, 0.0f);                                                     \
    x_out[n_ * FEAT + t] = y_ + xm##U;                                        \
}

__global__ __launch_bounds__(256, 2) void layer_kernel(
    const float* __restrict__ x_in, float* __restrict__ x_out,
    const int* __restrict__ row_ptr, const int* __restrict__ csr_pack,
    const float* __restrict__ rel_i,     // [128][32]
    const float* __restrict__ wg_i,      // [32][13][32] step-contiguous
    const float* __restrict__ blin_i, const float* __restrict__ g_i,
    const float* __restrict__ b_i,
    const float* __restrict__ dinv, const float* __restrict__ sc,
    const int* __restrict__ h0, const float* __restrict__ query) {
    int t  = threadIdx.x;
    int b  = t >> 5, dd = t & 31;
    int lane = t & 63;
    __shared__ float s_rel[NRELX2 * DDIM];   // 16 KB

    for (int k = t; k < NRELX2 * DDIM; k += 256) s_rel[k] = rel_i[k];

    float q   = query[t];
    int   h0b = h0[b];
    float gdd = g_i[dd], bdd = b_i[dd], bl = blin_i[dd];
    // rotate-down-by-1 within each 32-lane half of the wave (pull from lane+1)
    int bperm_addr = ((((lane + 1) & 31) | (lane & 32)) << 2);
    __syncthreads();

    int nbase = blockIdx.x * NPB;
    SDECL(0) SDECL(1) SDECL(2) SDECL(3) SDECL(4)
    SDECL(5) SDECL(6) SDECL(7) SDECL(8) SDECL(9)
    STATS_COMP(0, nbase + 0)
    STATS_COMP(1, nbase + 1)
    STATS_COMP(2, nbase + 2)
    STATS_COMP(3, nbase + 3)
    STATS_COMP(4, nbase + 4)
    STATS_COMP(5, nbase + 5)
    STATS_COMP(6, nbase + 6)
    STATS_COMP(7, nbase + 7)
    STATS_COMP(8, nbase + 8)
    STATS_COMP(9, nbase + 9)

    float acc0 = bl, acc1 = bl, acc2 = bl, acc3 = bl, acc4 = bl;
    float acc5 = bl, acc6 = bl, acc7 = bl, acc8 = bl, acc9 = bl;

    const float* wbase = wg_i + dd;
    float cw0, cw1, cw2, cw3, cw4, cw5, cw6, cw7, cw8, cw9, cw10, cw11, cw12;
    float nw0, nw1, nw2, nw3, nw4, nw5, nw6, nw7, nw8, nw9, nw10, nw11, nw12;
    LOADW(cw, wbase)   // step 0

    #pragma unroll 1
    for (int i = 0; i < 32; i += 2) {
        // phase A: prefetch step i+1 into nw, compute step i with cw
        const float* wnA = wbase + (i + 1) * 416;
        LOADW(nw, wnA)
        STEP_ALL(cw)
        // phase B: prefetch step i+2 into cw (wraps harmlessly at i=30),
        //          compute step i+1 with nw
        const float* wnB = wbase + ((i + 2) & 31) * 416;
        LOADW(cw, wnB)
        STEP_ALL(nw)
    }
    // 32 rotations = identity: lane dd again holds col dd

    LNSTORE(0, nbase + 0)
    LNSTORE(1, nbase + 1)
    LNSTORE(2, nbase + 2)
    LNSTORE(3, nbase + 3)
    LNSTORE(4, nbase + 4)
    LNSTORE(5, nbase + 5)
    LNSTORE(6, nbase + 6)
    LNSTORE(7, nbase + 7)
    LNSTORE(8, nbase + 8)
    LNSTORE(9, nbase + 9)
}

// ---------------------------------------------------------------- readout
__global__ void score_kernel(const float* __restrict__ x, const int* __restrict__ tnew,
                             const float* __restrict__ query,
                             const float* __restrict__ W1, const float* __restrict__ b1,
                             const float* __restrict__ W2, const float* __restrict__ b2,
                             float* __restrict__ out) {
    int idx = blockIdx.x;         // b*33+j
    int b = idx / NEG1;
    int k = threadIdx.x;          // 0..63
    __shared__ float v[64];
    int tnode = tnew[idx];
    if (k < 32) v[k] = x[tnode * FEAT + b * DDIM + k];
    else        v[k] = query[b * DDIM + (k - 32)];
    __syncthreads();
    float acc = b1[k];
    #pragma unroll
    for (int l = 0; l < 64; l++) acc = fmaf(v[l], W1[l * 64 + k], acc);
    acc = fmaxf(acc, 0.f);
    float p = acc * W2[k];
    #pragma unroll
    for (int m = 32; m >= 1; m >>= 1) p += __shfl_xor(p, m);
    if (k == 0) out[idx] = p + b2[0];
}

// ---------------------------------------------------------------- launch
extern "C" void kernel_launch(void* const* d_in, const int* in_sizes, int n_in,
                              void* d_out, int out_size, void* d_ws, size_t ws_size,
                              hipStream_t stream) {
    const int* edge_src  = (const int*)d_in[0];
    const int* edge_dst  = (const int*)d_in[1];
    const int* edge_type = (const int*)d_in[2];
    const int* h_index   = (const int*)d_in[3];
    const int* t_index   = (const int*)d_in[4];
    const int* r_index   = (const int*)d_in[5];
    const float* rel_query = (const float*)d_in[7];
    const float* Wrel    = (const float*)d_in[8];
    const float* brel    = (const float*)d_in[9];
    const float* Wlin    = (const float*)d_in[10];
    const float* blin    = (const float*)d_in[11];
    const float* ln_g    = (const float*)d_in[12];
    const float* ln_b    = (const float*)d_in[13];
    const float* W1      = (const float*)d_in[14];
    const float* b1      = (const float*)d_in[15];
    const float* W2      = (const float*)d_in[16];
    const float* b2      = (const float*)d_in[17];

    const int N  = NNODE;
    const int E  = in_sizes[0];
    const int E2 = 2 * E;

    char* p = (char*)d_ws;
    auto carve = [&](size_t bytes) {
        void* r = (void*)p;
        p += (bytes + 255) & ~(size_t)255;
        return r;
    };
    float* x0      = (float*)carve((size_t)N * FEAT * 4);
    float* x1      = (float*)carve((size_t)N * FEAT * 4);
    int*   cnt     = (int*)carve((size_t)N * 4);
    int*   row_ptr = (int*)carve((size_t)(N + 1) * 4);
    int*   cursor  = (int*)carve((size_t)N * 4);
    int*   csr_pack= (int*)carve((size_t)E2 * 4);
    float* dinv    = (float*)carve((size_t)N * 4);
    float* logdeg  = (float*)carve((size_t)N * 4);
    float* scn     = (float*)carve((size_t)N * 4);
    float* meanp   = (float*)carve(16);
    float* rel_all = (float*)carve((size_t)NLAYER * NRELX2 * DDIM * 4);
    float* wg      = (float*)carve((size_t)NLAYER * 32 * 13 * 32 * 4);
    int*   h0      = (int*)carve(BS * 4);
    int*   r0      = (int*)carve(BS * 4);
    float* query   = (float*)carve(BS * DDIM * 4);
    int*   tnew    = (int*)carve(BS * NEG1 * 4);

    hipMemsetAsync(cnt, 0, (size_t)N * 4, stream);
    hipMemsetAsync(cursor, 0, (size_t)N * 4, stream);

    int eb = (E2 + 255) / 256;
    count_kernel<<<eb, 256, 0, stream>>>(edge_src, edge_dst, cnt, E);
    scan_kernel<<<1, 1024, 0, stream>>>(cnt, row_ptr, N);
    fill_kernel<<<eb, 256, 0, stream>>>(edge_src, edge_dst, edge_type, row_ptr,
                                        cursor, csr_pack, E);
    deg_kernel<<<(N + 255) / 256, 256, 0, stream>>>(cnt, dinv, logdeg, N);
    mean_kernel<<<1, 256, 0, stream>>>(logdeg, meanp, N);
    sc_kernel<<<(N + 255) / 256, 256, 0, stream>>>(logdeg, meanp, scn, N);
    prep_kernel<<<1, 256, 0, stream>>>(h_index, t_index, r_index, rel_query,
                                       h0, r0, query, tnew);
    rel_kernel<<<(NLAYER * NRELX2 * DDIM + 255) / 256, 256, 0, stream>>>(
        rel_query, Wrel, brel, rel_all);
    wg_kernel<<<(NLAYER * 32 * 13 * 32 + 255) / 256, 256, 0, stream>>>(Wlin, wg);
    init_x_kernel<<<(N * FEAT + 255) / 256, 256, 0, stream>>>(x0, h0, query);

    float* xin = x0;
    float* xout = x1;
    for (int i = 0; i < NLAYER; ++i) {
        layer_kernel<<<N / NPB, 256, 0, stream>>>(
            xin, xout, row_ptr, csr_pack,
            rel_all + (size_t)i * NRELX2 * DDIM,
            wg + (size_t)i * 32 * 13 * 32,
            blin + (size_t)i * DDIM,
            ln_g + (size_t)i * DDIM,
            ln_b + (size_t)i * DDIM,
            dinv, scn, h0, query);
        float* tmp = xin; xin = xout; xout = tmp;
    }

    score_kernel<<<BS * NEG1, 64, 0, stream>>>(xin, tnew, query, W1, b1, W2, b2,
                                               (float*)d_out);
}

// Round 16
// 529.889 us; speedup vs baseline: 1.4663x; 1.2351x over previous
//
#include <hip/hip_runtime.h>
#include <hip/hip_bf16.h>

// Problem constants fixed by setup_inputs()
#define NNODE   20000
#define BS      8
#define NEG1    33
#define DDIM    32
#define NLAYER  6
#define NRELX2  128     // 2*N_REL
#define FEAT    256     // BS*DDIM
#define INW     416     // 13*DDIM
#define NPB     4       // nodes per block -> 32 A-rows, grid 5000
#define BPSZ    (13 * 2 * 2 * 64 * 8)   // per-layer packed-B ushorts (26624)

typedef __attribute__((ext_vector_type(8))) short s16x8;
typedef __attribute__((ext_vector_type(4))) float f32x4;

__device__ inline unsigned short bf16_rn(float f) {
    unsigned u = __float_as_uint(f);
    u += 0x7FFF + ((u >> 16) & 1);
    return (unsigned short)(u >> 16);
}
__device__ inline float bf16_f(unsigned short h) {
    return __uint_as_float(((unsigned)h) << 16);
}

// ---------------------------------------------------------------- precompute
__global__ void count_kernel(const int* __restrict__ es, const int* __restrict__ ed,
                             int* __restrict__ cnt, int E) {
    int i = blockIdx.x * 256 + threadIdx.x;
    if (i >= 2 * E) return;
    int dst = (i < E) ? ed[i] : es[i - E];
    atomicAdd(&cnt[dst], 1);
}

__global__ void scan_kernel(const int* __restrict__ cnt, int* __restrict__ row_ptr, int N) {
    __shared__ int sh[1024];
    __shared__ int s_carry;
    if (threadIdx.x == 0) { s_carry = 0; row_ptr[0] = 0; }
    __syncthreads();
    for (int base = 0; base < N; base += 1024) {
        int i = base + threadIdx.x;
        int v = (i < N) ? cnt[i] : 0;
        sh[threadIdx.x] = v;
        __syncthreads();
        for (int off = 1; off < 1024; off <<= 1) {
            int t = (threadIdx.x >= off) ? sh[threadIdx.x - off] : 0;
            __syncthreads();
            sh[threadIdx.x] += t;
            __syncthreads();
        }
        int carry = s_carry;
        if (i < N) row_ptr[i + 1] = carry + sh[threadIdx.x];
        __syncthreads();
        if (threadIdx.x == 1023) s_carry = carry + sh[1023];
        __syncthreads();
    }
}

// csr_pack = (src << 16) | etype   (src < 20000 < 65536, etype < 128)
__global__ void fill_kernel(const int* __restrict__ es, const int* __restrict__ ed,
                            const int* __restrict__ et, const int* __restrict__ row_ptr,
                            int* __restrict__ cursor, int* __restrict__ csr_pack, int E) {
    int i = blockIdx.x * 256 + threadIdx.x;
    if (i >= 2 * E) return;
    int src, dst, ty;
    if (i < E) { src = es[i]; dst = ed[i]; ty = et[i]; }
    else       { src = ed[i - E]; dst = es[i - E]; ty = et[i - E] + 64; }
    int pos = row_ptr[dst] + atomicAdd(&cursor[dst], 1);
    csr_pack[pos] = (src << 16) | ty;
}

__global__ void deg_kernel(const int* __restrict__ cnt, float* __restrict__ dinv,
                           float* __restrict__ logdeg, int N) {
    int n = blockIdx.x * 256 + threadIdx.x;
    if (n >= N) return;
    float deg = (float)cnt[n] + 1.0f;
    dinv[n] = 1.0f / deg;
    logdeg[n] = logf(deg);
}

__global__ void mean_kernel(const float* __restrict__ logdeg, float* __restrict__ meanout, int N) {
    __shared__ float sh[256];
    float s = 0.f;
    for (int i = threadIdx.x; i < N; i += 256) s += logdeg[i];
    sh[threadIdx.x] = s;
    __syncthreads();
    for (int off = 128; off > 0; off >>= 1) {
        if (threadIdx.x < off) sh[threadIdx.x] += sh[threadIdx.x + off];
        __syncthreads();
    }
    if (threadIdx.x == 0) meanout[0] = sh[0] / (float)N;
}

__global__ void sc_kernel(const float* __restrict__ logdeg, const float* __restrict__ meanp,
                          float* __restrict__ sc, int N) {
    int n = blockIdx.x * 256 + threadIdx.x;
    if (n >= N) return;
    sc[n] = logdeg[n] / meanp[0];
}

__global__ void prep_kernel(const int* __restrict__ h_index, const int* __restrict__ t_index,
                            const int* __restrict__ r_index, const float* __restrict__ rel_query,
                            int* __restrict__ h0, int* __restrict__ r0,
                            float* __restrict__ query, int* __restrict__ tnew) {
    __shared__ int s_isneg[BS];
    __shared__ int s_r0[BS];
    int t = threadIdx.x;
    if (t < BS) {
        int b = t;
        int hv = h_index[b * NEG1];
        int all = 1;
        for (int j = 1; j < NEG1; j++) all &= (h_index[b * NEG1 + j] == hv);
        s_isneg[b] = all;
        int h0v = all ? hv : t_index[b * NEG1];
        int r0v = all ? r_index[b * NEG1] : r_index[b * NEG1] + 64;
        s_r0[b] = r0v;
        h0[b] = h0v;
        r0[b] = r0v;
    }
    __syncthreads();
    {
        int b = t >> 5, dd = t & 31;
        query[t] = rel_query[s_r0[b] * DDIM + dd];
    }
    for (int idx = t; idx < BS * NEG1; idx += 256) {
        int b = idx / NEG1;
        tnew[idx] = s_isneg[b] ? t_index[idx] : h_index[idx];
    }
}

__global__ void rel_kernel(const float* __restrict__ rel_query, const float* __restrict__ Wrel,
                           const float* __restrict__ brel, float* __restrict__ rel_all) {
    int idx = blockIdx.x * 256 + threadIdx.x;
    if (idx >= NLAYER * NRELX2 * DDIM) return;
    int i  = idx >> 12;          // / 4096
    int q  = (idx >> 5) & 127;
    int dd = idx & 31;
    float acc = brel[i * DDIM + dd];
    #pragma unroll
    for (int k = 0; k < DDIM; k++)
        acc = fmaf(rel_query[q * DDIM + k], Wrel[i * DDIM * DDIM + k * DDIM + dd], acc);
    rel_all[idx] = acc;
}

// Packed split-bf16 B fragments for mfma_f32_16x16x32_bf16.
// Flat layout: ((((layer*13 + j)*2 + half)*2 + term)*64 + lane)*8 + e
// j=0: W rows 0..31 (x part). j=1..12: s=(j-1)&3, scl=(j-1)>>2,
//   W row = 32 + (kk*4+s)*3 + scl, where kk = (lane>>4)*8+e is the feature idx.
// col = half*16 + (lane&15). term0 = bf16 hi, term1 = bf16 lo.
__global__ void bpack_kernel(const float* __restrict__ Wlin, unsigned short* __restrict__ bp) {
    int idx = blockIdx.x * 256 + threadIdx.x;
    if (idx >= NLAYER * BPSZ) return;
    int e    = idx & 7;
    int lane = (idx >> 3) & 63;
    int term = (idx >> 9) & 1;
    int half = (idx >> 10) & 1;
    int jl   = idx >> 11;
    int j    = jl % 13;
    int layer = jl / 13;
    int col = half * 16 + (lane & 15);
    int kk  = (lane >> 4) * 8 + e;
    int row;
    if (j == 0) row = kk;
    else { int s = (j - 1) & 3, scl = (j - 1) >> 2; row = 32 + (kk * 4 + s) * 3 + scl; }
    float wv = Wlin[(layer * INW + row) * DDIM + col];
    unsigned short hi = bf16_rn(wv);
    bp[idx] = (term == 0) ? hi : bf16_rn(wv - bf16_f(hi));
}

__global__ void init_x_kernel(float* __restrict__ x, const int* __restrict__ h0,
                              const float* __restrict__ query) {
    int i = blockIdx.x * 256 + threadIdx.x;
    if (i >= NNODE * FEAT) return;
    int n = i >> 8;
    int t = i & 255;
    int b = t >> 5;
    x[i] = (h0[b] == n) ? query[t] : 0.f;
}

// ---------------------------------------------------------------- main layer
// Phases: [rel->LDS] [stats x4 nodes] [A(split bf16)->LDS] [MFMA GEMM]
// [LN/residual]. GEMM: out = G0 + sv*G1 + s2*G2 over compact 160-wide A;
// 13 K-chunks x 3 split terms = 39 MFMA per wave (tile,half).

#define STATS_COMP(U, NODE) {                                                 \
    int n_ = (NODE);                                                          \
    float bv_ = (h0b == n_) ? q : 0.f;                                        \
    float sum_ = bv_, ssq_ = bv_ * bv_, vmx_ = bv_, vmn_ = bv_;               \
    int e0_ = row_ptr[n_], e1_ = row_ptr[n_ + 1];                             \
    xm##U = x_in[n_ * FEAT + t];                                              \
    int e_ = e0_;                                                             \
    for (; e_ + 3 < e1_; e_ += 4) {                                           \
        int pa_ = csr_pack[e_];                                               \
        int pb_ = csr_pack[e_ + 1];                                           \
        int pc_ = csr_pack[e_ + 2];                                           \
        int pd_ = csr_pack[e_ + 3];                                           \
        float xa_ = x_in[(pa_ >> 16) * FEAT + t];                             \
        float xb_ = x_in[(pb_ >> 16) * FEAT + t];                             \
        float xc_ = x_in[(pc_ >> 16) * FEAT + t];                             \
        float xd_ = x_in[(pd_ >> 16) * FEAT + t];                             \
        float ra_ = s_relC[((pa_ & 0xFFFF) << 5) + dd];                       \
        float rb_ = s_relC[((pb_ & 0xFFFF) << 5) + dd];                       \
        float rc_ = s_relC[((pc_ & 0xFFFF) << 5) + dd];                       \
        float rd_ = s_relC[((pd_ & 0xFFFF) << 5) + dd];                       \
        float ma_ = xa_ * ra_, mb_ = xb_ * rb_;                               \
        float mc_ = xc_ * rc_, md_ = xd_ * rd_;                               \
        sum_ += ((ma_ + mb_) + (mc_ + md_));                                  \
        ssq_ = fmaf(ma_, ma_, ssq_); ssq_ = fmaf(mb_, mb_, ssq_);             \
        ssq_ = fmaf(mc_, mc_, ssq_); ssq_ = fmaf(md_, md_, ssq_);             \
        vmx_ = fmaxf(vmx_, fmaxf(fmaxf(ma_, mb_), fmaxf(mc_, md_)));         \
        vmn_ = fminf(vmn_, fminf(fminf(ma_, mb_), fminf(mc_, md_)));         \
    }                                                                         \
    for (; e_ < e1_; ++e_) {                                                  \
        int p_  = csr_pack[e_];                                               \
        float m_ = x_in[(p_ >> 16) * FEAT + t]                                \
                   * s_relC[((p_ & 0xFFFF) << 5) + dd];                       \
        sum_ += m_; ssq_ = fmaf(m_, m_, ssq_);                                \
        vmx_ = fmaxf(vmx_, m_); vmn_ = fminf(vmn_, m_);                       \
    }                                                                         \
    float dv_ = dinv[n_];                                                     \
    mean##U = sum_ * dv_;                                                     \
    float sq_ = ssq_ * dv_;                                                   \
    mx##U = vmx_; mn##U = vmn_;                                               \
    sd##U = sqrtf(fmaxf(sq_ - mean##U * mean##U, 1e-6f));                     \
    float sv_ = sc[n_];                                                       \
    sv##U = sv_; s2##U = 1.0f / fmaxf(sv_, 0.01f);                            \
}

#define SDECL(U) float xm##U, mean##U, mx##U, mn##U, sd##U, sv##U, s2##U;

#define AW1(ROW, C, V) {                                                      \
    unsigned short h_ = bf16_rn(V);                                           \
    s_A[0][ROW][(C) * 32 + dd] = h_;                                          \
    s_A[1][ROW][(C) * 32 + dd] = bf16_rn((V) - bf16_f(h_));                   \
}

#define AWRITE(U, NL) {                                                       \
    int row_ = (NL) * 8 + b;                                                  \
    AW1(row_, 0, xm##U)                                                       \
    AW1(row_, 1, mean##U)                                                     \
    AW1(row_, 2, mx##U)                                                       \
    AW1(row_, 3, mn##U)                                                       \
    AW1(row_, 4, sd##U)                                                       \
}

#define LNF(U, NL) {                                                          \
    int row_ = (NL) * 8 + b;                                                  \
    float v_ = s_relC[row_ * 33 + dd]                                         \
             + sv##U * s_relC[1056 + row_ * 33 + dd]                          \
             + s2##U * s_relC[2112 + row_ * 33 + dd] + bl;                    \
    float s1_ = v_;                                                           \
    s1_ += __shfl_xor(s1_, 16, 32); s1_ += __shfl_xor(s1_, 8, 32);            \
    s1_ += __shfl_xor(s1_, 4, 32);  s1_ += __shfl_xor(s1_, 2, 32);            \
    s1_ += __shfl_xor(s1_, 1, 32);                                            \
    float lm_ = s1_ * (1.0f / 32.0f);                                         \
    float dl_ = v_ - lm_;                                                     \
    float p2_ = dl_ * dl_;                                                    \
    p2_ += __shfl_xor(p2_, 16, 32); p2_ += __shfl_xor(p2_, 8, 32);            \
    p2_ += __shfl_xor(p2_, 4, 32);  p2_ += __shfl_xor(p2_, 2, 32);            \
    p2_ += __shfl_xor(p2_, 1, 32);                                            \
    float var_ = p2_ * (1.0f / 32.0f);                                        \
    float y_ = dl_ / sqrtf(var_ + 1e-5f) * gdd + bdd;                         \
    y_ = fmaxf(y_, 0.0f);                                                     \
    x_out[(nbase + (NL)) * FEAT + t] = y_ + xm##U;                            \
}

__global__ __launch_bounds__(256, 2) void layer_kernel(
    const float* __restrict__ x_in, float* __restrict__ x_out,
    const int* __restrict__ row_ptr, const int* __restrict__ csr_pack,
    const float* __restrict__ rel_i,           // [128][32]
    const unsigned short* __restrict__ bp_i,   // packed split-bf16 B frags
    const float* __restrict__ blin_i, const float* __restrict__ g_i,
    const float* __restrict__ b_i,
    const float* __restrict__ dinv, const float* __restrict__ sc,
    const int* __restrict__ h0, const float* __restrict__ query) {
    int t  = threadIdx.x;
    int b  = t >> 5, dd = t & 31;
    int l  = t & 63;
    int w  = t >> 6;
    __shared__ float s_relC[4096];                          // 16 KB: rel, then C planes
    __shared__ __align__(16) unsigned short s_A[2][32][168]; // 21 KB split-bf16 A

    // phase 0: rel table
    for (int k = t; k < NRELX2 * DDIM; k += 256) s_relC[k] = rel_i[k];

    float q   = query[t];
    int   h0b = h0[b];
    float gdd = g_i[dd], bdd = b_i[dd], bl = blin_i[dd];
    __syncthreads();

    int nbase = blockIdx.x * NPB;
    SDECL(0) SDECL(1) SDECL(2) SDECL(3)
    STATS_COMP(0, nbase + 0)
    STATS_COMP(1, nbase + 1)
    STATS_COMP(2, nbase + 2)
    STATS_COMP(3, nbase + 3)

    // phase 2: A rows (split bf16) into LDS
    AWRITE(0, 0) AWRITE(1, 1) AWRITE(2, 2) AWRITE(3, 3)
    __syncthreads();

    // phase 3: MFMA GEMM. wave w: tile = w>>1, half = w&1.
    {
        int tile = w >> 1, half = w & 1;
        int arow = tile * 16 + (l & 15);
        int koff = (l >> 4) * 8;
        f32x4 acc0 = {0.f, 0.f, 0.f, 0.f};
        f32x4 acc1 = {0.f, 0.f, 0.f, 0.f};
        f32x4 acc2 = {0.f, 0.f, 0.f, 0.f};
        #pragma unroll
        for (int j = 0; j < 13; ++j) {
            int ac = (j == 0) ? 0 : 1 + ((j - 1) & 3);
            s16x8 ah = *(const s16x8*)&s_A[0][arow][ac * 32 + koff];
            s16x8 al = *(const s16x8*)&s_A[1][arow][ac * 32 + koff];
            const unsigned short* pb = bp_i + (((j * 2 + half) * 2 + 0) * 64 + l) * 8;
            s16x8 bh = *(const s16x8*)pb;
            s16x8 bl2 = *(const s16x8*)(pb + 512);   // term=1 stride 64*8
            if (j <= 4) {
                acc0 = __builtin_amdgcn_mfma_f32_16x16x32_bf16(ah, bh,  acc0, 0, 0, 0);
                acc0 = __builtin_amdgcn_mfma_f32_16x16x32_bf16(ah, bl2, acc0, 0, 0, 0);
                acc0 = __builtin_amdgcn_mfma_f32_16x16x32_bf16(al, bh,  acc0, 0, 0, 0);
            } else if (j <= 8) {
                acc1 = __builtin_amdgcn_mfma_f32_16x16x32_bf16(ah, bh,  acc1, 0, 0, 0);
                acc1 = __builtin_amdgcn_mfma_f32_16x16x32_bf16(ah, bl2, acc1, 0, 0, 0);
                acc1 = __builtin_amdgcn_mfma_f32_16x16x32_bf16(al, bh,  acc1, 0, 0, 0);
            } else {
                acc2 = __builtin_amdgcn_mfma_f32_16x16x32_bf16(ah, bh,  acc2, 0, 0, 0);
                acc2 = __builtin_amdgcn_mfma_f32_16x16x32_bf16(ah, bl2, acc2, 0, 0, 0);
                acc2 = __builtin_amdgcn_mfma_f32_16x16x32_bf16(al, bh,  acc2, 0, 0, 0);
            }
        }
        __syncthreads();   // rel region no longer needed; safe to overwrite with C
        // C/D layout (verified): col = lane&15, row = (lane>>4)*4 + reg
        int crow = tile * 16 + ((l >> 4) << 2);
        int ccol = half * 16 + (l & 15);
        #pragma unroll
        for (int r = 0; r < 4; ++r) {
            s_relC[(crow + r) * 33 + ccol]        = acc0[r];
            s_relC[1056 + (crow + r) * 33 + ccol] = acc1[r];
            s_relC[2112 + (crow + r) * 33 + ccol] = acc2[r];
        }
    }
    __syncthreads();

    // phase 4: combine + LayerNorm + ReLU + residual
    LNF(0, 0) LNF(1, 1) LNF(2, 2) LNF(3, 3)
}

// ---------------------------------------------------------------- readout
__global__ void score_kernel(const float* __restrict__ x, const int* __restrict__ tnew,
                             const float* __restrict__ query,
                             const float* __restrict__ W1, const float* __restrict__ b1,
                             const float* __restrict__ W2, const float* __restrict__ b2,
                             float* __restrict__ out) {
    int idx = blockIdx.x;         // b*33+j
    int b = idx / NEG1;
    int k = threadIdx.x;          // 0..63
    __shared__ float v[64];
    int tnode = tnew[idx];
    if (k < 32) v[k] = x[tnode * FEAT + b * DDIM + k];
    else        v[k] = query[b * DDIM + (k - 32)];
    __syncthreads();
    float acc = b1[k];
    #pragma unroll
    for (int l = 0; l < 64; l++) acc = fmaf(v[l], W1[l * 64 + k], acc);
    acc = fmaxf(acc, 0.f);
    float p = acc * W2[k];
    #pragma unroll
    for (int m = 32; m >= 1; m >>= 1) p += __shfl_xor(p, m);
    if (k == 0) out[idx] = p + b2[0];
}

// ---------------------------------------------------------------- launch
extern "C" void kernel_launch(void* const* d_in, const int* in_sizes, int n_in,
                              void* d_out, int out_size, void* d_ws, size_t ws_size,
                              hipStream_t stream) {
    const int* edge_src  = (const int*)d_in[0];
    const int* edge_dst  = (const int*)d_in[1];
    const int* edge_type = (const int*)d_in[2];
    const int* h_index   = (const int*)d_in[3];
    const int* t_index   = (const int*)d_in[4];
    const int* r_index   = (const int*)d_in[5];
    const float* rel_query = (const float*)d_in[7];
    const float* Wrel    = (const float*)d_in[8];
    const float* brel    = (const float*)d_in[9];
    const float* Wlin    = (const float*)d_in[10];
    const float* blin    = (const float*)d_in[11];
    const float* ln_g    = (const float*)d_in[12];
    const float* ln_b    = (const float*)d_in[13];
    const float* W1      = (const float*)d_in[14];
    const float* b1      = (const float*)d_in[15];
    const float* W2      = (const float*)d_in[16];
    const float* b2      = (const float*)d_in[17];

    const int N  = NNODE;
    const int E  = in_sizes[0];
    const int E2 = 2 * E;

    char* p = (char*)d_ws;
    auto carve = [&](size_t bytes) {
        void* r = (void*)p;
        p += (bytes + 255) & ~(size_t)255;
        return r;
    };
    float* x0      = (float*)carve((size_t)N * FEAT * 4);
    float* x1      = (float*)carve((size_t)N * FEAT * 4);
    int*   cnt     = (int*)carve((size_t)N * 4);
    int*   row_ptr = (int*)carve((size_t)(N + 1) * 4);
    int*   cursor  = (int*)carve((size_t)N * 4);
    int*   csr_pack= (int*)carve((size_t)E2 * 4);
    float* dinv    = (float*)carve((size_t)N * 4);
    float* logdeg  = (float*)carve((size_t)N * 4);
    float* scn     = (float*)carve((size_t)N * 4);
    float* meanp   = (float*)carve(16);
    float* rel_all = (float*)carve((size_t)NLAYER * NRELX2 * DDIM * 4);
    unsigned short* bp = (unsigned short*)carve((size_t)NLAYER * BPSZ * 2);
    int*   h0      = (int*)carve(BS * 4);
    int*   r0      = (int*)carve(BS * 4);
    float* query   = (float*)carve(BS * DDIM * 4);
    int*   tnew    = (int*)carve(BS * NEG1 * 4);

    hipMemsetAsync(cnt, 0, (size_t)N * 4, stream);
    hipMemsetAsync(cursor, 0, (size_t)N * 4, stream);

    int eb = (E2 + 255) / 256;
    count_kernel<<<eb, 256, 0, stream>>>(edge_src, edge_dst, cnt, E);
    scan_kernel<<<1, 1024, 0, stream>>>(cnt, row_ptr, N);
    fill_kernel<<<eb, 256, 0, stream>>>(edge_src, edge_dst, edge_type, row_ptr,
                                        cursor, csr_pack, E);
    deg_kernel<<<(N + 255) / 256, 256, 0, stream>>>(cnt, dinv, logdeg, N);
    mean_kernel<<<1, 256, 0, stream>>>(logdeg, meanp, N);
    sc_kernel<<<(N + 255) / 256, 256, 0, stream>>>(logdeg, meanp, scn, N);
    prep_kernel<<<1, 256, 0, stream>>>(h_index, t_index, r_index, rel_query,
                                       h0, r0, query, tnew);
    rel_kernel<<<(NLAYER * NRELX2 * DDIM + 255) / 256, 256, 0, stream>>>(
        rel_query, Wrel, brel, rel_all);
    bpack_kernel<<<(NLAYER * BPSZ + 255) / 256, 256, 0, stream>>>(Wlin, bp);
    init_x_kernel<<<(N * FEAT + 255) / 256, 256, 0, stream>>>(x0, h0, query);

    float* xin = x0;
    float* xout = x1;
    for (int i = 0; i < NLAYER; ++i) {
        layer_kernel<<<N / NPB, 256, 0, stream>>>(
            xin, xout, row_ptr, csr_pack,
            rel_all + (size_t)i * NRELX2 * DDIM,
            bp + (size_t)i * BPSZ,
            blin + (size_t)i * DDIM,
            ln_g + (size_t)i * DDIM,
            ln_b + (size_t)i * DDIM,
            dinv, scn, h0, query);
        float* tmp = xin; xin = xout; xout = tmp;
    }

    score_kernel<<<BS * NEG1, 64, 0, stream>>>(xin, tnew, query, W1, b1, W2, b2,
                                               (float*)d_out);
}

// Round 17
// 435.604 us; speedup vs baseline: 1.7837x; 1.2164x over previous
//
#include <hip/hip_runtime.h>
#include <hip/hip_bf16.h>

// Problem constants fixed by setup_inputs()
#define NNODE   20000
#define BS      8
#define NEG1    33
#define DDIM    32
#define NLAYER  6
#define NRELX2  128     // 2*N_REL
#define FEAT    256     // BS*DDIM
#define INW     416     // 13*DDIM
#define NPB     4       // nodes per block -> 32 A-rows, grid 5000
#define BPSZ    (13 * 2 * 2 * 64 * 8)   // per-layer packed-B ushorts (26624)

typedef __attribute__((ext_vector_type(8))) short s16x8;
typedef __attribute__((ext_vector_type(4))) float f32x4;

__device__ inline unsigned short bf16_rn(float f) {
    unsigned u = __float_as_uint(f);
    u += 0x7FFF + ((u >> 16) & 1);
    return (unsigned short)(u >> 16);
}
__device__ inline float bf16_f(unsigned short h) {
    return __uint_as_float(((unsigned)h) << 16);
}

// ---------------------------------------------------------------- precompute
__global__ void count_kernel(const int* __restrict__ es, const int* __restrict__ ed,
                             int* __restrict__ cnt, int E) {
    int i = blockIdx.x * 256 + threadIdx.x;
    if (i >= 2 * E) return;
    int dst = (i < E) ? ed[i] : es[i - E];
    atomicAdd(&cnt[dst], 1);
}

__global__ void scan_kernel(const int* __restrict__ cnt, int* __restrict__ row_ptr, int N) {
    __shared__ int sh[1024];
    __shared__ int s_carry;
    if (threadIdx.x == 0) { s_carry = 0; row_ptr[0] = 0; }
    __syncthreads();
    for (int base = 0; base < N; base += 1024) {
        int i = base + threadIdx.x;
        int v = (i < N) ? cnt[i] : 0;
        sh[threadIdx.x] = v;
        __syncthreads();
        for (int off = 1; off < 1024; off <<= 1) {
            int t = (threadIdx.x >= off) ? sh[threadIdx.x - off] : 0;
            __syncthreads();
            sh[threadIdx.x] += t;
            __syncthreads();
        }
        int carry = s_carry;
        if (i < N) row_ptr[i + 1] = carry + sh[threadIdx.x];
        __syncthreads();
        if (threadIdx.x == 1023) s_carry = carry + sh[1023];
        __syncthreads();
    }
}

// csr_pack = (src << 16) | etype   (src < 20000 < 65536, etype < 128)
__global__ void fill_kernel(const int* __restrict__ es, const int* __restrict__ ed,
                            const int* __restrict__ et, const int* __restrict__ row_ptr,
                            int* __restrict__ cursor, int* __restrict__ csr_pack, int E) {
    int i = blockIdx.x * 256 + threadIdx.x;
    if (i >= 2 * E) return;
    int src, dst, ty;
    if (i < E) { src = es[i]; dst = ed[i]; ty = et[i]; }
    else       { src = ed[i - E]; dst = es[i - E]; ty = et[i - E] + 64; }
    int pos = row_ptr[dst] + atomicAdd(&cursor[dst], 1);
    csr_pack[pos] = (src << 16) | ty;
}

__global__ void deg_kernel(const int* __restrict__ cnt, float* __restrict__ dinv,
                           float* __restrict__ logdeg, int N) {
    int n = blockIdx.x * 256 + threadIdx.x;
    if (n >= N) return;
    float deg = (float)cnt[n] + 1.0f;
    dinv[n] = 1.0f / deg;
    logdeg[n] = logf(deg);
}

__global__ void mean_kernel(const float* __restrict__ logdeg, float* __restrict__ meanout, int N) {
    __shared__ float sh[256];
    float s = 0.f;
    for (int i = threadIdx.x; i < N; i += 256) s += logdeg[i];
    sh[threadIdx.x] = s;
    __syncthreads();
    for (int off = 128; off > 0; off >>= 1) {
        if (threadIdx.x < off) sh[threadIdx.x] += sh[threadIdx.x + off];
        __syncthreads();
    }
    if (threadIdx.x == 0) meanout[0] = sh[0] / (float)N;
}

__global__ void sc_kernel(const float* __restrict__ logdeg, const float* __restrict__ meanp,
                          float* __restrict__ sc, int N) {
    int n = blockIdx.x * 256 + threadIdx.x;
    if (n >= N) return;
    sc[n] = logdeg[n] / meanp[0];
}

__global__ void prep_kernel(const int* __restrict__ h_index, const int* __restrict__ t_index,
                            const int* __restrict__ r_index, const float* __restrict__ rel_query,
                            int* __restrict__ h0, int* __restrict__ r0,
                            float* __restrict__ query, int* __restrict__ tnew) {
    __shared__ int s_isneg[BS];
    __shared__ int s_r0[BS];
    int t = threadIdx.x;
    if (t < BS) {
        int b = t;
        int hv = h_index[b * NEG1];
        int all = 1;
        for (int j = 1; j < NEG1; j++) all &= (h_index[b * NEG1 + j] == hv);
        s_isneg[b] = all;
        int h0v = all ? hv : t_index[b * NEG1];
        int r0v = all ? r_index[b * NEG1] : r_index[b * NEG1] + 64;
        s_r0[b] = r0v;
        h0[b] = h0v;
        r0[b] = r0v;
    }
    __syncthreads();
    {
        int b = t >> 5, dd = t & 31;
        query[t] = rel_query[s_r0[b] * DDIM + dd];
    }
    for (int idx = t; idx < BS * NEG1; idx += 256) {
        int b = idx / NEG1;
        tnew[idx] = s_isneg[b] ? t_index[idx] : h_index[idx];
    }
}

__global__ void rel_kernel(const float* __restrict__ rel_query, const float* __restrict__ Wrel,
                           const float* __restrict__ brel, float* __restrict__ rel_all) {
    int idx = blockIdx.x * 256 + threadIdx.x;
    if (idx >= NLAYER * NRELX2 * DDIM) return;
    int i  = idx >> 12;          // / 4096
    int q  = (idx >> 5) & 127;
    int dd = idx & 31;
    float acc = brel[i * DDIM + dd];
    #pragma unroll
    for (int k = 0; k < DDIM; k++)
        acc = fmaf(rel_query[q * DDIM + k], Wrel[i * DDIM * DDIM + k * DDIM + dd], acc);
    rel_all[idx] = acc;
}

// Packed split-bf16 B fragments for mfma_f32_16x16x32_bf16.
// Flat layout: ((((layer*13 + j)*2 + half)*2 + term)*64 + lane)*8 + e
// j=0: W rows 0..31 (x part). j=1..12: s=(j-1)&3, scl=(j-1)>>2,
//   W row = 32 + (kk*4+s)*3 + scl, where kk = (lane>>4)*8+e is the feature idx.
// col = half*16 + (lane&15). term0 = bf16 hi, term1 = bf16 lo.
__global__ void bpack_kernel(const float* __restrict__ Wlin, unsigned short* __restrict__ bp) {
    int idx = blockIdx.x * 256 + threadIdx.x;
    if (idx >= NLAYER * BPSZ) return;
    int e    = idx & 7;
    int lane = (idx >> 3) & 63;
    int term = (idx >> 9) & 1;
    int half = (idx >> 10) & 1;
    int jl   = idx >> 11;
    int j    = jl % 13;
    int layer = jl / 13;
    int col = half * 16 + (lane & 15);
    int kk  = (lane >> 4) * 8 + e;
    int row;
    if (j == 0) row = kk;
    else { int s = (j - 1) & 3, scl = (j - 1) >> 2; row = 32 + (kk * 4 + s) * 3 + scl; }
    float wv = Wlin[(layer * INW + row) * DDIM + col];
    unsigned short hi = bf16_rn(wv);
    bp[idx] = (term == 0) ? hi : bf16_rn(wv - bf16_f(hi));
}

__global__ void init_x_kernel(float* __restrict__ x, const int* __restrict__ h0,
                              const float* __restrict__ query) {
    int i = blockIdx.x * 256 + threadIdx.x;
    if (i >= NNODE * FEAT) return;
    int n = i >> 8;
    int t = i & 255;
    int b = t >> 5;
    x[i] = (h0[b] == n) ? query[t] : 0.f;
}

// ---------------------------------------------------------------- main layer
// Phases: [stats x4 nodes (rel read from L1-resident global)] [A(split bf16)
// ->LDS] [MFMA GEMM] [C overlaid into A region] [LN/residual].
// LDS = 21.5 KB only -> ~7 blocks/CU for latency hiding.

#define STATS_COMP(U, NODE) {                                                 \
    int n_ = (NODE);                                                          \
    float bv_ = (h0b == n_) ? q : 0.f;                                        \
    float sum_ = bv_, ssq_ = bv_ * bv_, vmx_ = bv_, vmn_ = bv_;               \
    int e0_ = row_ptr[n_], e1_ = row_ptr[n_ + 1];                             \
    xm##U = x_in[n_ * FEAT + t];                                              \
    int e_ = e0_;                                                             \
    for (; e_ + 3 < e1_; e_ += 4) {                                           \
        int pa_ = csr_pack[e_];                                               \
        int pb_ = csr_pack[e_ + 1];                                           \
        int pc_ = csr_pack[e_ + 2];                                           \
        int pd_ = csr_pack[e_ + 3];                                           \
        float xa_ = x_in[(pa_ >> 16) * FEAT + t];                             \
        float xb_ = x_in[(pb_ >> 16) * FEAT + t];                             \
        float xc_ = x_in[(pc_ >> 16) * FEAT + t];                             \
        float xd_ = x_in[(pd_ >> 16) * FEAT + t];                             \
        float ra_ = rel_i[((pa_ & 0xFFFF) << 5) + dd];                        \
        float rb_ = rel_i[((pb_ & 0xFFFF) << 5) + dd];                        \
        float rc_ = rel_i[((pc_ & 0xFFFF) << 5) + dd];                        \
        float rd_ = rel_i[((pd_ & 0xFFFF) << 5) + dd];                        \
        float ma_ = xa_ * ra_, mb_ = xb_ * rb_;                               \
        float mc_ = xc_ * rc_, md_ = xd_ * rd_;                               \
        sum_ += ((ma_ + mb_) + (mc_ + md_));                                  \
        ssq_ = fmaf(ma_, ma_, ssq_); ssq_ = fmaf(mb_, mb_, ssq_);             \
        ssq_ = fmaf(mc_, mc_, ssq_); ssq_ = fmaf(md_, md_, ssq_);             \
        vmx_ = fmaxf(vmx_, fmaxf(fmaxf(ma_, mb_), fmaxf(mc_, md_)));         \
        vmn_ = fminf(vmn_, fminf(fminf(ma_, mb_), fminf(mc_, md_)));         \
    }                                                                         \
    for (; e_ < e1_; ++e_) {                                                  \
        int p_  = csr_pack[e_];                                               \
        float m_ = x_in[(p_ >> 16) * FEAT + t]                                \
                   * rel_i[((p_ & 0xFFFF) << 5) + dd];                        \
        sum_ += m_; ssq_ = fmaf(m_, m_, ssq_);                                \
        vmx_ = fmaxf(vmx_, m_); vmn_ = fminf(vmn_, m_);                       \
    }                                                                         \
    float dv_ = dinv[n_];                                                     \
    mean##U = sum_ * dv_;                                                     \
    float sq_ = ssq_ * dv_;                                                   \
    mx##U = vmx_; mn##U = vmn_;                                               \
    sd##U = sqrtf(fmaxf(sq_ - mean##U * mean##U, 1e-6f));                     \
    float sv_ = sc[n_];                                                       \
    sv##U = sv_; s2##U = 1.0f / fmaxf(sv_, 0.01f);                            \
}

#define SDECL(U) float xm##U, mean##U, mx##U, mn##U, sd##U, sv##U, s2##U;

#define AW1(ROW, C, V) {                                                      \
    unsigned short h_ = bf16_rn(V);                                           \
    s_A[0][ROW][(C) * 32 + dd] = h_;                                          \
    s_A[1][ROW][(C) * 32 + dd] = bf16_rn((V) - bf16_f(h_));                   \
}

#define AWRITE(U, NL) {                                                       \
    int row_ = (NL) * 8 + b;                                                  \
    AW1(row_, 0, xm##U)                                                       \
    AW1(row_, 1, mean##U)                                                     \
    AW1(row_, 2, mx##U)                                                       \
    AW1(row_, 3, mn##U)                                                       \
    AW1(row_, 4, sd##U)                                                       \
}

#define LNF(U, NL) {                                                          \
    int row_ = (NL) * 8 + b;                                                  \
    float v_ = s_C[row_ * 33 + dd]                                            \
             + sv##U * s_C[1056 + row_ * 33 + dd]                             \
             + s2##U * s_C[2112 + row_ * 33 + dd] + bl;                       \
    float s1_ = v_;                                                           \
    s1_ += __shfl_xor(s1_, 16, 32); s1_ += __shfl_xor(s1_, 8, 32);            \
    s1_ += __shfl_xor(s1_, 4, 32);  s1_ += __shfl_xor(s1_, 2, 32);            \
    s1_ += __shfl_xor(s1_, 1, 32);                                            \
    float lm_ = s1_ * (1.0f / 32.0f);                                         \
    float dl_ = v_ - lm_;                                                     \
    float p2_ = dl_ * dl_;                                                    \
    p2_ += __shfl_xor(p2_, 16, 32); p2_ += __shfl_xor(p2_, 8, 32);            \
    p2_ += __shfl_xor(p2_, 4, 32);  p2_ += __shfl_xor(p2_, 2, 32);            \
    p2_ += __shfl_xor(p2_, 1, 32);                                            \
    float var_ = p2_ * (1.0f / 32.0f);                                        \
    float y_ = dl_ / sqrtf(var_ + 1e-5f) * gdd + bdd;                         \
    y_ = fmaxf(y_, 0.0f);                                                     \
    x_out[(nbase + (NL)) * FEAT + t] = y_ + xm##U;                            \
}

__global__ __launch_bounds__(256, 6) void layer_kernel(
    const float* __restrict__ x_in, float* __restrict__ x_out,
    const int* __restrict__ row_ptr, const int* __restrict__ csr_pack,
    const float* __restrict__ rel_i,           // [128][32], L1-resident
    const unsigned short* __restrict__ bp_i,   // packed split-bf16 B frags
    const float* __restrict__ blin_i, const float* __restrict__ g_i,
    const float* __restrict__ b_i,
    const float* __restrict__ dinv, const float* __restrict__ sc,
    const int* __restrict__ h0, const float* __restrict__ query) {
    int t  = threadIdx.x;
    int b  = t >> 5, dd = t & 31;
    int l  = t & 63;
    int w  = t >> 6;
    // 21 KB: split-bf16 A; C planes (12.7 KB) overlay it after MFMA reads.
    __shared__ __align__(16) unsigned short s_A[2][32][168];
    float* s_C = (float*)&s_A[0][0][0];

    float q   = query[t];
    int   h0b = h0[b];
    float gdd = g_i[dd], bdd = b_i[dd], bl = blin_i[dd];

    int nbase = blockIdx.x * NPB;
    SDECL(0) SDECL(1) SDECL(2) SDECL(3)
    STATS_COMP(0, nbase + 0)
    STATS_COMP(1, nbase + 1)
    STATS_COMP(2, nbase + 2)
    STATS_COMP(3, nbase + 3)

    // phase 2: A rows (split bf16) into LDS
    AWRITE(0, 0) AWRITE(1, 1) AWRITE(2, 2) AWRITE(3, 3)
    __syncthreads();

    // phase 3: MFMA GEMM. wave w: tile = w>>1, half = w&1.
    {
        int tile = w >> 1, half = w & 1;
        int arow = tile * 16 + (l & 15);
        int koff = (l >> 4) * 8;
        f32x4 acc0 = {0.f, 0.f, 0.f, 0.f};
        f32x4 acc1 = {0.f, 0.f, 0.f, 0.f};
        f32x4 acc2 = {0.f, 0.f, 0.f, 0.f};
        #pragma unroll
        for (int j = 0; j < 13; ++j) {
            int ac = (j == 0) ? 0 : 1 + ((j - 1) & 3);
            s16x8 ah = *(const s16x8*)&s_A[0][arow][ac * 32 + koff];
            s16x8 al = *(const s16x8*)&s_A[1][arow][ac * 32 + koff];
            const unsigned short* pb = bp_i + (((j * 2 + half) * 2 + 0) * 64 + l) * 8;
            s16x8 bh = *(const s16x8*)pb;
            s16x8 bl2 = *(const s16x8*)(pb + 512);   // term=1 stride 64*8
            if (j <= 4) {
                acc0 = __builtin_amdgcn_mfma_f32_16x16x32_bf16(ah, bh,  acc0, 0, 0, 0);
                acc0 = __builtin_amdgcn_mfma_f32_16x16x32_bf16(ah, bl2, acc0, 0, 0, 0);
                acc0 = __builtin_amdgcn_mfma_f32_16x16x32_bf16(al, bh,  acc0, 0, 0, 0);
            } else if (j <= 8) {
                acc1 = __builtin_amdgcn_mfma_f32_16x16x32_bf16(ah, bh,  acc1, 0, 0, 0);
                acc1 = __builtin_amdgcn_mfma_f32_16x16x32_bf16(ah, bl2, acc1, 0, 0, 0);
                acc1 = __builtin_amdgcn_mfma_f32_16x16x32_bf16(al, bh,  acc1, 0, 0, 0);
            } else {
                acc2 = __builtin_amdgcn_mfma_f32_16x16x32_bf16(ah, bh,  acc2, 0, 0, 0);
                acc2 = __builtin_amdgcn_mfma_f32_16x16x32_bf16(ah, bl2, acc2, 0, 0, 0);
                acc2 = __builtin_amdgcn_mfma_f32_16x16x32_bf16(al, bh,  acc2, 0, 0, 0);
            }
        }
        __syncthreads();   // all waves done reading A -> safe to overlay C
        // C/D layout (verified): col = lane&15, row = (lane>>4)*4 + reg
        int crow = tile * 16 + ((l >> 4) << 2);
        int ccol = half * 16 + (l & 15);
        #pragma unroll
        for (int r = 0; r < 4; ++r) {
            s_C[(crow + r) * 33 + ccol]        = acc0[r];
            s_C[1056 + (crow + r) * 33 + ccol] = acc1[r];
            s_C[2112 + (crow + r) * 33 + ccol] = acc2[r];
        }
    }
    __syncthreads();

    // phase 4: combine + LayerNorm + ReLU + residual
    LNF(0, 0) LNF(1, 1) LNF(2, 2) LNF(3, 3)
}

// ---------------------------------------------------------------- readout
__global__ void score_kernel(const float* __restrict__ x, const int* __restrict__ tnew,
                             const float* __restrict__ query,
                             const float* __restrict__ W1, const float* __restrict__ b1,
                             const float* __restrict__ W2, const float* __restrict__ b2,
                             float* __restrict__ out) {
    int idx = blockIdx.x;         // b*33+j
    int b = idx / NEG1;
    int k = threadIdx.x;          // 0..63
    __shared__ float v[64];
    int tnode = tnew[idx];
    if (k < 32) v[k] = x[tnode * FEAT + b * DDIM + k];
    else        v[k] = query[b * DDIM + (k - 32)];
    __syncthreads();
    float acc = b1[k];
    #pragma unroll
    for (int l = 0; l < 64; l++) acc = fmaf(v[l], W1[l * 64 + k], acc);
    acc = fmaxf(acc, 0.f);
    float p = acc * W2[k];
    #pragma unroll
    for (int m = 32; m >= 1; m >>= 1) p += __shfl_xor(p, m);
    if (k == 0) out[idx] = p + b2[0];
}

// ---------------------------------------------------------------- launch
extern "C" void kernel_launch(void* const* d_in, const int* in_sizes, int n_in,
                              void* d_out, int out_size, void* d_ws, size_t ws_size,
                              hipStream_t stream) {
    const int* edge_src  = (const int*)d_in[0];
    const int* edge_dst  = (const int*)d_in[1];
    const int* edge_type = (const int*)d_in[2];
    const int* h_index   = (const int*)d_in[3];
    const int* t_index   = (const int*)d_in[4];
    const int* r_index   = (const int*)d_in[5];
    const float* rel_query = (const float*)d_in[7];
    const float* Wrel    = (const float*)d_in[8];
    const float* brel    = (const float*)d_in[9];
    const float* Wlin    = (const float*)d_in[10];
    const float* blin    = (const float*)d_in[11];
    const float* ln_g    = (const float*)d_in[12];
    const float* ln_b    = (const float*)d_in[13];
    const float* W1      = (const float*)d_in[14];
    const float* b1      = (const float*)d_in[15];
    const float* W2      = (const float*)d_in[16];
    const float* b2      = (const float*)d_in[17];

    const int N  = NNODE;
    const int E  = in_sizes[0];
    const int E2 = 2 * E;

    char* p = (char*)d_ws;
    auto carve = [&](size_t bytes) {
        void* r = (void*)p;
        p += (bytes + 255) & ~(size_t)255;
        return r;
    };
    float* x0      = (float*)carve((size_t)N * FEAT * 4);
    float* x1      = (float*)carve((size_t)N * FEAT * 4);
    int*   cnt     = (int*)carve((size_t)N * 4);
    int*   row_ptr = (int*)carve((size_t)(N + 1) * 4);
    int*   cursor  = (int*)carve((size_t)N * 4);
    int*   csr_pack= (int*)carve((size_t)E2 * 4);
    float* dinv    = (float*)carve((size_t)N * 4);
    float* logdeg  = (float*)carve((size_t)N * 4);
    float* scn     = (float*)carve((size_t)N * 4);
    float* meanp   = (float*)carve(16);
    float* rel_all = (float*)carve((size_t)NLAYER * NRELX2 * DDIM * 4);
    unsigned short* bp = (unsigned short*)carve((size_t)NLAYER * BPSZ * 2);
    int*   h0      = (int*)carve(BS * 4);
    int*   r0      = (int*)carve(BS * 4);
    float* query   = (float*)carve(BS * DDIM * 4);
    int*   tnew    = (int*)carve(BS * NEG1 * 4);

    hipMemsetAsync(cnt, 0, (size_t)N * 4, stream);
    hipMemsetAsync(cursor, 0, (size_t)N * 4, stream);

    int eb = (E2 + 255) / 256;
    count_kernel<<<eb, 256, 0, stream>>>(edge_src, edge_dst, cnt, E);
    scan_kernel<<<1, 1024, 0, stream>>>(cnt, row_ptr, N);
    fill_kernel<<<eb, 256, 0, stream>>>(edge_src, edge_dst, edge_type, row_ptr,
                                        cursor, csr_pack, E);
    deg_kernel<<<(N + 255) / 256, 256, 0, stream>>>(cnt, dinv, logdeg, N);
    mean_kernel<<<1, 256, 0, stream>>>(logdeg, meanp, N);
    sc_kernel<<<(N + 255) / 256, 256, 0, stream>>>(logdeg, meanp, scn, N);
    prep_kernel<<<1, 256, 0, stream>>>(h_index, t_index, r_index, rel_query,
                                       h0, r0, query, tnew);
    rel_kernel<<<(NLAYER * NRELX2 * DDIM + 255) / 256, 256, 0, stream>>>(
        rel_query, Wrel, brel, rel_all);
    bpack_kernel<<<(NLAYER * BPSZ + 255) / 256, 256, 0, stream>>>(Wlin, bp);
    init_x_kernel<<<(N * FEAT + 255) / 256, 256, 0, stream>>>(x0, h0, query);

    float* xin = x0;
    float* xout = x1;
    for (int i = 0; i < NLAYER; ++i) {
        layer_kernel<<<N / NPB, 256, 0, stream>>>(
            xin, xout, row_ptr, csr_pack,
            rel_all + (size_t)i * NRELX2 * DDIM,
            bp + (size_t)i * BPSZ,
            blin + (size_t)i * DDIM,
            ln_g + (size_t)i * DDIM,
            ln_b + (size_t)i * DDIM,
            dinv, scn, h0, query);
        float* tmp = xin; xin = xout; xout = tmp;
    }

    score_kernel<<<BS * NEG1, 64, 0, stream>>>(xin, tnew, query, W1, b1, W2, b2,
                                               (float*)d_out);
}

// Round 18
// 408.358 us; speedup vs baseline: 1.9027x; 1.0667x over previous
//
#include <hip/hip_runtime.h>
#include <hip/hip_bf16.h>

// Problem constants fixed by setup_inputs()
#define NNODE   20000
#define BS      8
#define NEG1    33
#define DDIM    32
#define NLAYER  6
#define NRELX2  128     // 2*N_REL
#define FEAT    256     // BS*DDIM
#define INW     416     // 13*DDIM
#define NPB     4       // nodes per block -> 32 A-rows, grid 5000
#define BPSZ    (13 * 2 * 2 * 64 * 8)   // per-layer packed-B ushorts (26624)
#define SCB     ((NNODE + 255) / 256)   // scan blocks (79)

typedef __attribute__((ext_vector_type(8))) short s16x8;
typedef __attribute__((ext_vector_type(4))) float f32x4;

__device__ inline unsigned short bf16_rn(float f) {
    unsigned u = __float_as_uint(f);
    u += 0x7FFF + ((u >> 16) & 1);
    return (unsigned short)(u >> 16);
}
__device__ inline float bf16_f(unsigned short h) {
    return __uint_as_float(((unsigned)h) << 16);
}

// ---------------------------------------------------------------- precompute
__global__ void count_kernel(const int* __restrict__ es, const int* __restrict__ ed,
                             int* __restrict__ cnt, int E) {
    int i = blockIdx.x * 256 + threadIdx.x;
    if (i >= 2 * E) return;
    int dst = (i < E) ? ed[i] : es[i - E];
    atomicAdd(&cnt[dst], 1);
}

// hierarchical scan: A) per-block inclusive scan + block sums
__global__ void scanA_kernel(const int* __restrict__ cnt, int* __restrict__ row_ptr,
                             int* __restrict__ bsum, int N) {
    __shared__ int sh[256];
    int i = blockIdx.x * 256 + threadIdx.x;
    int v = (i < N) ? cnt[i] : 0;
    sh[threadIdx.x] = v;
    __syncthreads();
    #pragma unroll
    for (int off = 1; off < 256; off <<= 1) {
        int t = (threadIdx.x >= off) ? sh[threadIdx.x - off] : 0;
        __syncthreads();
        sh[threadIdx.x] += t;
        __syncthreads();
    }
    if (i < N) row_ptr[i + 1] = sh[threadIdx.x];
    if (threadIdx.x == 255) bsum[blockIdx.x] = sh[255];
}

// B) exclusive scan of block sums (one small block)
__global__ void scanB_kernel(int* __restrict__ bsum, int NB) {
    __shared__ int sh[128];
    int t = threadIdx.x;
    int v = (t < NB) ? bsum[t] : 0;
    sh[t] = v;
    __syncthreads();
    #pragma unroll
    for (int off = 1; off < 128; off <<= 1) {
        int x = (t >= off) ? sh[t - off] : 0;
        __syncthreads();
        sh[t] += x;
        __syncthreads();
    }
    if (t < NB) bsum[t] = sh[t] - v;   // exclusive
}

// C) add block offsets
__global__ void scanC_kernel(const int* __restrict__ bsum, int* __restrict__ row_ptr, int N) {
    int i = blockIdx.x * 256 + threadIdx.x;
    if (i == 0) row_ptr[0] = 0;
    if (i < N) row_ptr[i + 1] += bsum[blockIdx.x];
}

// csr_pack = (src << 16) | etype   (src < 20000 < 65536, etype < 128)
__global__ void fill_kernel(const int* __restrict__ es, const int* __restrict__ ed,
                            const int* __restrict__ et, const int* __restrict__ row_ptr,
                            int* __restrict__ cursor, int* __restrict__ csr_pack, int E) {
    int i = blockIdx.x * 256 + threadIdx.x;
    if (i >= 2 * E) return;
    int src, dst, ty;
    if (i < E) { src = es[i]; dst = ed[i]; ty = et[i]; }
    else       { src = ed[i - E]; dst = es[i - E]; ty = et[i - E] + 64; }
    int pos = row_ptr[dst] + atomicAdd(&cursor[dst], 1);
    csr_pack[pos] = (src << 16) | ty;
}

__global__ void deg_kernel(const int* __restrict__ cnt, float* __restrict__ dinv,
                           float* __restrict__ logdeg, int N) {
    int n = blockIdx.x * 256 + threadIdx.x;
    if (n >= N) return;
    float deg = (float)cnt[n] + 1.0f;
    dinv[n] = 1.0f / deg;
    logdeg[n] = logf(deg);
}

__global__ void mean_kernel(const float* __restrict__ logdeg, float* __restrict__ meanout, int N) {
    __shared__ float sh[256];
    float s = 0.f;
    for (int i = threadIdx.x; i < N; i += 256) s += logdeg[i];
    sh[threadIdx.x] = s;
    __syncthreads();
    for (int off = 128; off > 0; off >>= 1) {
        if (threadIdx.x < off) sh[threadIdx.x] += sh[threadIdx.x + off];
        __syncthreads();
    }
    if (threadIdx.x == 0) meanout[0] = sh[0] / (float)N;
}

__global__ void sc_kernel(const float* __restrict__ logdeg, const float* __restrict__ meanp,
                          float* __restrict__ sc, int N) {
    int n = blockIdx.x * 256 + threadIdx.x;
    if (n >= N) return;
    sc[n] = logdeg[n] / meanp[0];
}

__global__ void prep_kernel(const int* __restrict__ h_index, const int* __restrict__ t_index,
                            const int* __restrict__ r_index, const float* __restrict__ rel_query,
                            int* __restrict__ h0, int* __restrict__ r0,
                            float* __restrict__ query, int* __restrict__ tnew) {
    __shared__ int s_isneg[BS];
    __shared__ int s_r0[BS];
    int t = threadIdx.x;
    if (t < BS) {
        int b = t;
        int hv = h_index[b * NEG1];
        int all = 1;
        for (int j = 1; j < NEG1; j++) all &= (h_index[b * NEG1 + j] == hv);
        s_isneg[b] = all;
        int h0v = all ? hv : t_index[b * NEG1];
        int r0v = all ? r_index[b * NEG1] : r_index[b * NEG1] + 64;
        s_r0[b] = r0v;
        h0[b] = h0v;
        r0[b] = r0v;
    }
    __syncthreads();
    {
        int b = t >> 5, dd = t & 31;
        query[t] = rel_query[s_r0[b] * DDIM + dd];
    }
    for (int idx = t; idx < BS * NEG1; idx += 256) {
        int b = idx / NEG1;
        tnew[idx] = s_isneg[b] ? t_index[idx] : h_index[idx];
    }
}

__global__ void rel_kernel(const float* __restrict__ rel_query, const float* __restrict__ Wrel,
                           const float* __restrict__ brel, float* __restrict__ rel_all) {
    int idx = blockIdx.x * 256 + threadIdx.x;
    if (idx >= NLAYER * NRELX2 * DDIM) return;
    int i  = idx >> 12;          // / 4096
    int q  = (idx >> 5) & 127;
    int dd = idx & 31;
    float acc = brel[i * DDIM + dd];
    #pragma unroll
    for (int k = 0; k < DDIM; k++)
        acc = fmaf(rel_query[q * DDIM + k], Wrel[i * DDIM * DDIM + k * DDIM + dd], acc);
    rel_all[idx] = acc;
}

// Packed split-bf16 B fragments for mfma_f32_16x16x32_bf16.
// Flat layout: ((((layer*13 + j)*2 + half)*2 + term)*64 + lane)*8 + e
__global__ void bpack_kernel(const float* __restrict__ Wlin, unsigned short* __restrict__ bp) {
    int idx = blockIdx.x * 256 + threadIdx.x;
    if (idx >= NLAYER * BPSZ) return;
    int e    = idx & 7;
    int lane = (idx >> 3) & 63;
    int term = (idx >> 9) & 1;
    int half = (idx >> 10) & 1;
    int jl   = idx >> 11;
    int j    = jl % 13;
    int layer = jl / 13;
    int col = half * 16 + (lane & 15);
    int kk  = (lane >> 4) * 8 + e;
    int row;
    if (j == 0) row = kk;
    else { int s = (j - 1) & 3, scl = (j - 1) >> 2; row = 32 + (kk * 4 + s) * 3 + scl; }
    float wv = Wlin[(layer * INW + row) * DDIM + col];
    unsigned short hi = bf16_rn(wv);
    bp[idx] = (term == 0) ? hi : bf16_rn(wv - bf16_f(hi));
}

__global__ void init_x_kernel(float* __restrict__ x, const int* __restrict__ h0,
                              const float* __restrict__ query) {
    int i = blockIdx.x * 256 + threadIdx.x;
    if (i >= NNODE * FEAT) return;
    int n = i >> 8;
    int t = i & 255;
    int b = t >> 5;
    x[i] = (h0[b] == n) ? query[t] : 0.f;
}

// ---------------------------------------------------------------- main layer
// Phases: [stats x4 nodes (rel read from L1-resident global)] [A(split bf16)
// ->LDS] [MFMA GEMM] [C overlaid into A region] [LN/residual].
// LDS = 21.5 KB only -> ~7 blocks/CU for latency hiding.

#define STATS_COMP(U, NODE) {                                                 \
    int n_ = (NODE);                                                          \
    float bv_ = (h0b == n_) ? q : 0.f;                                        \
    float sum_ = bv_, ssq_ = bv_ * bv_, vmx_ = bv_, vmn_ = bv_;               \
    int e0_ = row_ptr[n_], e1_ = row_ptr[n_ + 1];                             \
    xm##U = x_in[n_ * FEAT + t];                                              \
    int e_ = e0_;                                                             \
    for (; e_ + 3 < e1_; e_ += 4) {                                           \
        int pa_ = csr_pack[e_];                                               \
        int pb_ = csr_pack[e_ + 1];                                           \
        int pc_ = csr_pack[e_ + 2];                                           \
        int pd_ = csr_pack[e_ + 3];                                           \
        float xa_ = x_in[(pa_ >> 16) * FEAT + t];                             \
        float xb_ = x_in[(pb_ >> 16) * FEAT + t];                             \
        float xc_ = x_in[(pc_ >> 16) * FEAT + t];                             \
        float xd_ = x_in[(pd_ >> 16) * FEAT + t];                             \
        float ra_ = rel_i[((pa_ & 0xFFFF) << 5) + dd];                        \
        float rb_ = rel_i[((pb_ & 0xFFFF) << 5) + dd];                        \
        float rc_ = rel_i[((pc_ & 0xFFFF) << 5) + dd];                        \
        float rd_ = rel_i[((pd_ & 0xFFFF) << 5) + dd];                        \
        float ma_ = xa_ * ra_, mb_ = xb_ * rb_;                               \
        float mc_ = xc_ * rc_, md_ = xd_ * rd_;                               \
        sum_ += ((ma_ + mb_) + (mc_ + md_));                                  \
        ssq_ = fmaf(ma_, ma_, ssq_); ssq_ = fmaf(mb_, mb_, ssq_);             \
        ssq_ = fmaf(mc_, mc_, ssq_); ssq_ = fmaf(md_, md_, ssq_);             \
        vmx_ = fmaxf(vmx_, fmaxf(fmaxf(ma_, mb_), fmaxf(mc_, md_)));         \
        vmn_ = fminf(vmn_, fminf(fminf(ma_, mb_), fminf(mc_, md_)));         \
    }                                                                         \
    for (; e_ < e1_; ++e_) {                                                  \
        int p_  = csr_pack[e_];                                               \
        float m_ = x_in[(p_ >> 16) * FEAT + t]                                \
                   * rel_i[((p_ & 0xFFFF) << 5) + dd];                        \
        sum_ += m_; ssq_ = fmaf(m_, m_, ssq_);                                \
        vmx_ = fmaxf(vmx_, m_); vmn_ = fminf(vmn_, m_);                       \
    }                                                                         \
    float dv_ = dinv[n_];                                                     \
    mean##U = sum_ * dv_;                                                     \
    float sq_ = ssq_ * dv_;                                                   \
    mx##U = vmx_; mn##U = vmn_;                                               \
    sd##U = sqrtf(fmaxf(sq_ - mean##U * mean##U, 1e-6f));                     \
    float sv_ = sc[n_];                                                       \
    sv##U = sv_; s2##U = 1.0f / fmaxf(sv_, 0.01f);                            \
}

#define SDECL(U) float xm##U, mean##U, mx##U, mn##U, sd##U, sv##U, s2##U;

#define AW1(ROW, C, V) {                                                      \
    unsigned short h_ = bf16_rn(V);                                           \
    s_A[0][ROW][(C) * 32 + dd] = h_;                                          \
    s_A[1][ROW][(C) * 32 + dd] = bf16_rn((V) - bf16_f(h_));                   \
}

#define AWRITE(U, NL) {                                                       \
    int row_ = (NL) * 8 + b;                                                  \
    AW1(row_, 0, xm##U)                                                       \
    AW1(row_, 1, mean##U)                                                     \
    AW1(row_, 2, mx##U)                                                       \
    AW1(row_, 3, mn##U)                                                       \
    AW1(row_, 4, sd##U)                                                       \
}

#define LNF(U, NL) {                                                          \
    int row_ = (NL) * 8 + b;                                                  \
    float v_ = s_C[row_ * 33 + dd]                                            \
             + sv##U * s_C[1056 + row_ * 33 + dd]                             \
             + s2##U * s_C[2112 + row_ * 33 + dd] + bl;                       \
    float s1_ = v_;                                                           \
    s1_ += __shfl_xor(s1_, 16, 32); s1_ += __shfl_xor(s1_, 8, 32);            \
    s1_ += __shfl_xor(s1_, 4, 32);  s1_ += __shfl_xor(s1_, 2, 32);            \
    s1_ += __shfl_xor(s1_, 1, 32);                                            \
    float lm_ = s1_ * (1.0f / 32.0f);                                         \
    float dl_ = v_ - lm_;                                                     \
    float p2_ = dl_ * dl_;                                                    \
    p2_ += __shfl_xor(p2_, 16, 32); p2_ += __shfl_xor(p2_, 8, 32);            \
    p2_ += __shfl_xor(p2_, 4, 32);  p2_ += __shfl_xor(p2_, 2, 32);            \
    p2_ += __shfl_xor(p2_, 1, 32);                                            \
    float var_ = p2_ * (1.0f / 32.0f);                                        \
    float y_ = dl_ / sqrtf(var_ + 1e-5f) * gdd + bdd;                         \
    y_ = fmaxf(y_, 0.0f);                                                     \
    x_out[(nbase + (NL)) * FEAT + t] = y_ + xm##U;                            \
}

__global__ __launch_bounds__(256, 6) void layer_kernel(
    const float* __restrict__ x_in, float* __restrict__ x_out,
    const int* __restrict__ row_ptr, const int* __restrict__ csr_pack,
    const float* __restrict__ rel_i,           // [128][32], L1-resident
    const unsigned short* __restrict__ bp_i,   // packed split-bf16 B frags
    const float* __restrict__ blin_i, const float* __restrict__ g_i,
    const float* __restrict__ b_i,
    const float* __restrict__ dinv, const float* __restrict__ sc,
    const int* __restrict__ h0, const float* __restrict__ query) {
    int t  = threadIdx.x;
    int b  = t >> 5, dd = t & 31;
    int l  = t & 63;
    int w  = t >> 6;
    // 21 KB: split-bf16 A; C planes (12.7 KB) overlay it after MFMA reads.
    __shared__ __align__(16) unsigned short s_A[2][32][168];
    float* s_C = (float*)&s_A[0][0][0];

    float q   = query[t];
    int   h0b = h0[b];
    float gdd = g_i[dd], bdd = b_i[dd], bl = blin_i[dd];

    int nbase = blockIdx.x * NPB;
    SDECL(0) SDECL(1) SDECL(2) SDECL(3)
    STATS_COMP(0, nbase + 0)
    STATS_COMP(1, nbase + 1)
    STATS_COMP(2, nbase + 2)
    STATS_COMP(3, nbase + 3)

    // phase 2: A rows (split bf16) into LDS
    AWRITE(0, 0) AWRITE(1, 1) AWRITE(2, 2) AWRITE(3, 3)
    __syncthreads();

    // phase 3: MFMA GEMM. wave w: tile = w>>1, half = w&1.
    {
        int tile = w >> 1, half = w & 1;
        int arow = tile * 16 + (l & 15);
        int koff = (l >> 4) * 8;
        f32x4 acc0 = {0.f, 0.f, 0.f, 0.f};
        f32x4 acc1 = {0.f, 0.f, 0.f, 0.f};
        f32x4 acc2 = {0.f, 0.f, 0.f, 0.f};
        #pragma unroll
        for (int j = 0; j < 13; ++j) {
            int ac = (j == 0) ? 0 : 1 + ((j - 1) & 3);
            s16x8 ah = *(const s16x8*)&s_A[0][arow][ac * 32 + koff];
            s16x8 al = *(const s16x8*)&s_A[1][arow][ac * 32 + koff];
            const unsigned short* pb = bp_i + (((j * 2 + half) * 2 + 0) * 64 + l) * 8;
            s16x8 bh = *(const s16x8*)pb;
            s16x8 bl2 = *(const s16x8*)(pb + 512);   // term=1 stride 64*8
            if (j <= 4) {
                acc0 = __builtin_amdgcn_mfma_f32_16x16x32_bf16(ah, bh,  acc0, 0, 0, 0);
                acc0 = __builtin_amdgcn_mfma_f32_16x16x32_bf16(ah, bl2, acc0, 0, 0, 0);
                acc0 = __builtin_amdgcn_mfma_f32_16x16x32_bf16(al, bh,  acc0, 0, 0, 0);
            } else if (j <= 8) {
                acc1 = __builtin_amdgcn_mfma_f32_16x16x32_bf16(ah, bh,  acc1, 0, 0, 0);
                acc1 = __builtin_amdgcn_mfma_f32_16x16x32_bf16(ah, bl2, acc1, 0, 0, 0);
                acc1 = __builtin_amdgcn_mfma_f32_16x16x32_bf16(al, bh,  acc1, 0, 0, 0);
            } else {
                acc2 = __builtin_amdgcn_mfma_f32_16x16x32_bf16(ah, bh,  acc2, 0, 0, 0);
                acc2 = __builtin_amdgcn_mfma_f32_16x16x32_bf16(ah, bl2, acc2, 0, 0, 0);
                acc2 = __builtin_amdgcn_mfma_f32_16x16x32_bf16(al, bh,  acc2, 0, 0, 0);
            }
        }
        __syncthreads();   // all waves done reading A -> safe to overlay C
        // C/D layout (verified): col = lane&15, row = (lane>>4)*4 + reg
        int crow = tile * 16 + ((l >> 4) << 2);
        int ccol = half * 16 + (l & 15);
        #pragma unroll
        for (int r = 0; r < 4; ++r) {
            s_C[(crow + r) * 33 + ccol]        = acc0[r];
            s_C[1056 + (crow + r) * 33 + ccol] = acc1[r];
            s_C[2112 + (crow + r) * 33 + ccol] = acc2[r];
        }
    }
    __syncthreads();

    // phase 4: combine + LayerNorm + ReLU + residual
    LNF(0, 0) LNF(1, 1) LNF(2, 2) LNF(3, 3)
}

// ---------------------------------------------------------------- readout
__global__ void score_kernel(const float* __restrict__ x, const int* __restrict__ tnew,
                             const float* __restrict__ query,
                             const float* __restrict__ W1, const float* __restrict__ b1,
                             const float* __restrict__ W2, const float* __restrict__ b2,
                             float* __restrict__ out) {
    int idx = blockIdx.x;         // b*33+j
    int b = idx / NEG1;
    int k = threadIdx.x;          // 0..63
    __shared__ float v[64];
    int tnode = tnew[idx];
    if (k < 32) v[k] = x[tnode * FEAT + b * DDIM + k];
    else        v[k] = query[b * DDIM + (k - 32)];
    __syncthreads();
    float acc = b1[k];
    #pragma unroll
    for (int l = 0; l < 64; l++) acc = fmaf(v[l], W1[l * 64 + k], acc);
    acc = fmaxf(acc, 0.f);
    float p = acc * W2[k];
    #pragma unroll
    for (int m = 32; m >= 1; m >>= 1) p += __shfl_xor(p, m);
    if (k == 0) out[idx] = p + b2[0];
}

// ---------------------------------------------------------------- launch
extern "C" void kernel_launch(void* const* d_in, const int* in_sizes, int n_in,
                              void* d_out, int out_size, void* d_ws, size_t ws_size,
                              hipStream_t stream) {
    const int* edge_src  = (const int*)d_in[0];
    const int* edge_dst  = (const int*)d_in[1];
    const int* edge_type = (const int*)d_in[2];
    const int* h_index   = (const int*)d_in[3];
    const int* t_index   = (const int*)d_in[4];
    const int* r_index   = (const int*)d_in[5];
    const float* rel_query = (const float*)d_in[7];
    const float* Wrel    = (const float*)d_in[8];
    const float* brel    = (const float*)d_in[9];
    const float* Wlin    = (const float*)d_in[10];
    const float* blin    = (const float*)d_in[11];
    const float* ln_g    = (const float*)d_in[12];
    const float* ln_b    = (const float*)d_in[13];
    const float* W1      = (const float*)d_in[14];
    const float* b1      = (const float*)d_in[15];
    const float* W2      = (const float*)d_in[16];
    const float* b2      = (const float*)d_in[17];

    const int N  = NNODE;
    const int E  = in_sizes[0];
    const int E2 = 2 * E;

    char* p = (char*)d_ws;
    auto carve = [&](size_t bytes) {
        void* r = (void*)p;
        p += (bytes + 255) & ~(size_t)255;
        return r;
    };
    float* x0      = (float*)carve((size_t)N * FEAT * 4);
    float* x1      = (float*)carve((size_t)N * FEAT * 4);
    int*   cnt     = (int*)carve((size_t)N * 4);
    int*   row_ptr = (int*)carve((size_t)(N + 1) * 4);
    int*   cursor  = (int*)carve((size_t)N * 4);
    int*   bsum    = (int*)carve((size_t)128 * 4);
    int*   csr_pack= (int*)carve((size_t)E2 * 4);
    float* dinv    = (float*)carve((size_t)N * 4);
    float* logdeg  = (float*)carve((size_t)N * 4);
    float* scn     = (float*)carve((size_t)N * 4);
    float* meanp   = (float*)carve(16);
    float* rel_all = (float*)carve((size_t)NLAYER * NRELX2 * DDIM * 4);
    unsigned short* bp = (unsigned short*)carve((size_t)NLAYER * BPSZ * 2);
    int*   h0      = (int*)carve(BS * 4);
    int*   r0      = (int*)carve(BS * 4);
    float* query   = (float*)carve(BS * DDIM * 4);
    int*   tnew    = (int*)carve(BS * NEG1 * 4);

    hipMemsetAsync(cnt, 0, (size_t)N * 4, stream);
    hipMemsetAsync(cursor, 0, (size_t)N * 4, stream);

    int eb = (E2 + 255) / 256;
    count_kernel<<<eb, 256, 0, stream>>>(edge_src, edge_dst, cnt, E);
    scanA_kernel<<<SCB, 256, 0, stream>>>(cnt, row_ptr, bsum, N);
    scanB_kernel<<<1, 128, 0, stream>>>(bsum, SCB);
    scanC_kernel<<<SCB, 256, 0, stream>>>(bsum, row_ptr, N);
    fill_kernel<<<eb, 256, 0, stream>>>(edge_src, edge_dst, edge_type, row_ptr,
                                        cursor, csr_pack, E);
    deg_kernel<<<(N + 255) / 256, 256, 0, stream>>>(cnt, dinv, logdeg, N);
    mean_kernel<<<1, 256, 0, stream>>>(logdeg, meanp, N);
    sc_kernel<<<(N + 255) / 256, 256, 0, stream>>>(logdeg, meanp, scn, N);
    prep_kernel<<<1, 256, 0, stream>>>(h_index, t_index, r_index, rel_query,
                                       h0, r0, query, tnew);
    rel_kernel<<<(NLAYER * NRELX2 * DDIM + 255) / 256, 256, 0, stream>>>(
        rel_query, Wrel, brel, rel_all);
    bpack_kernel<<<(NLAYER * BPSZ + 255) / 256, 256, 0, stream>>>(Wlin, bp);
    init_x_kernel<<<(N * FEAT + 255) / 256, 256, 0, stream>>>(x0, h0, query);

    float* xin = x0;
    float* xout = x1;
    for (int i = 0; i < NLAYER; ++i) {
        layer_kernel<<<N / NPB, 256, 0, stream>>>(
            xin, xout, row_ptr, csr_pack,
            rel_all + (size_t)i * NRELX2 * DDIM,
            bp + (size_t)i * BPSZ,
            blin + (size_t)i * DDIM,
            ln_g + (size_t)i * DDIM,
            ln_b + (size_t)i * DDIM,
            dinv, scn, h0, query);
        float* tmp = xin; xin = xout; xout = tmp;
    }

    score_kernel<<<BS * NEG1, 64, 0, stream>>>(xin, tnew, query, W1, b1, W2, b2,
                                               (float*)d_out);
}